// Round 5
// baseline (8249.019 us; speedup 1.0000x reference)
//
#include <hip/hip_runtime.h>

// Seq2Seq GRU: B=256, S=128, T=64, I=63, H=1024. Inputs fp32, output fp32.
// All GEMMs: bf16 hi+lo 3-term split emulation (~fp32 accuracy).
// Encoder: ONE persistent kernel, 128 steps, device-atomic grid barrier.
//   grid 256 (1 block/CU, all co-resident: 142 KB LDS), 512 thr = 8 waves:
//   2 K-groups (k<512 / k>=512) x 4 m-subtile waves -> 2 waves/SIMD.

typedef unsigned short u16;
typedef __attribute__((ext_vector_type(8))) short s8v;   // 8 x bf16 (4 VGPRs)
typedef __attribute__((ext_vector_type(4))) float f4v;   // MFMA acc
typedef __attribute__((ext_vector_type(4))) int  i4v;    // 16B copy unit

__device__ __forceinline__ float b2f(u16 u) {
    return __uint_as_float(((unsigned int)u) << 16);
}
__device__ __forceinline__ u16 f2b(float f) {   // round-to-nearest-even
    unsigned int x = __float_as_uint(f);
    unsigned int r = x + 0x7fffu + ((x >> 16) & 1u);
    return (u16)(r >> 16);
}
__device__ __forceinline__ float sigf(float x) {
    return 1.0f / (1.0f + __expf(-x));
}
__device__ __forceinline__ f4v mfma16(s8v a, s8v b, f4v c) {
    return __builtin_amdgcn_mfma_f32_16x16x32_bf16(a, b, c, 0, 0, 0);
}

// ---------------------------------------------------------------------------
__global__ void zero_ws(i4v* __restrict__ p, int n) {
    int i = blockIdx.x * blockDim.x + threadIdx.x;
    if (i < n) { i4v z = {0, 0, 0, 0}; p[i] = z; }
}

__global__ void conv_split(const float* __restrict__ s, u16* __restrict__ hi,
                           u16* __restrict__ lo, int n) {
    int i = blockIdx.x * blockDim.x + threadIdx.x;
    int st = gridDim.x * blockDim.x;
    for (; i < n; i += st) {
        float v = s[i];
        u16 h = f2b(v);
        hi[i] = h;
        lo[i] = f2b(v - b2f(h));
    }
}

// Wih (3072 x 63 fp32) -> padded (3072 x 64) hi+lo, col 63 = 0
__global__ void conv_wih_split_pad(const float* __restrict__ s,
                                   u16* __restrict__ hi, u16* __restrict__ lo) {
    int idx = blockIdx.x * blockDim.x + threadIdx.x;
    int row = idx >> 6, col = idx & 63;
    float v = (col < 63) ? s[(size_t)row * 63 + col] : 0.f;
    u16 h = f2b(v);
    hi[idx] = h;
    lo[idx] = f2b(v - b2f(h));
}

// proj_W (63 x 1024 fp32) -> padded (64 x 1024) hi+lo, row 63 = 0
__global__ void conv_pw_split_pad(const float* __restrict__ s,
                                  u16* __restrict__ hi, u16* __restrict__ lo) {
    int idx = blockIdx.x * blockDim.x + threadIdx.x;
    float v = (idx < 63 * 1024) ? s[idx] : 0.f;
    u16 h = f2b(v);
    hi[idx] = h;
    lo[idx] = f2b(v - b2f(h));
}

// ---------------------------------------------------------------------------
// Persistent encoder: 128 GRU steps in one kernel, grid barrier between steps.
__global__ __launch_bounds__(512, 1) void enc_persist(
    const u16* __restrict__ WhhH, const u16* __restrict__ WhhL,
    const u16* __restrict__ WihH, const u16* __restrict__ WihL,
    const float* __restrict__ bih, const float* __restrict__ bhh,
    const float* __restrict__ xenc,
    u16* __restrict__ h0hi, u16* __restrict__ h0lo,
    u16* __restrict__ h1hi, u16* __restrict__ h1lo,
    int* __restrict__ bar)
{
    __shared__ u16 WbH[2][48 * 264];   // per-k-group Whh-hi chunk (BK=256,+8 pad)
    __shared__ u16 WbL[2][48 * 264];
    __shared__ u16 XbH[64 * 72];
    __shared__ u16 XbL[64 * 72];
    __shared__ u16 WisH[48 * 72];
    __shared__ u16 WisL[48 * 72];
    __shared__ f4v red[4][3][64];      // k-group-1 partial accs (r,z,hn)

    const int tid  = threadIdx.x;
    const int lane = tid & 63;
    const int wave = tid >> 6;          // 0..7
    const int g    = wave >> 2;         // k-group: 0 -> k[0,512), 1 -> k[512,1024)
    const int wv   = wave & 3;          // m-subtile (16 rows)
    const int gtid = tid & 255;         // thread id within k-group
    const int lrow = lane & 15;
    const int lk8  = lane >> 4;
    const int mt = blockIdx.x & 3;
    const int jt = blockIdx.x >> 2;
    const int m0 = mt * 64;
    const int j0 = jt * 16;

    // ---- one-time: Wih slice into LDS
    if (tid < 192) {
        int wr = tid >> 2, qq = tid & 3;
        int grow = (wr >> 4) * 1024 + j0 + (wr & 15);
        const u16* wpH = WihH + (size_t)grow * 64 + qq * 16;
        const u16* wpL = WihL + (size_t)grow * 64 + qq * 16;
        *(i4v*)&WisH[wr * 72 + qq * 16]     = *(const i4v*)wpH;
        *(i4v*)&WisH[wr * 72 + qq * 16 + 8] = *(const i4v*)(wpH + 8);
        *(i4v*)&WisL[wr * 72 + qq * 16]     = *(const i4v*)wpL;
        *(i4v*)&WisL[wr * 72 + qq * 16 + 8] = *(const i4v*)(wpL + 8);
    }

    const int jcol = j0 + lrow;
    const float bhr = bhh[jcol], bhz = bhh[1024 + jcol], bhn = bhh[2048 + jcol];
    const float bir = bih[jcol], biz = bih[1024 + jcol], bin = bih[2048 + jcol];

    // staging geometry (group-local, 256 threads cover 48x256 elements)
    int srow[6], sp16[6], sgrow[6];
    #pragma unroll
    for (int i = 0; i < 6; ++i) {
        int c16 = i * 256 + gtid;
        srow[i] = c16 >> 5;
        sp16[i] = c16 & 31;
        sgrow[i] = (srow[i] >> 4) * 1024 + j0 + (srow[i] & 15);
    }

    int* cnt  = bar;
    int* flag = bar + 16;   // separate cacheline

    const size_t arow = (size_t)(m0 + wv * 16 + lrow) * 1024 + lk8 * 8;
    const int kbase = g * 512;

    for (int s = 0; s < 128; ++s) {
        const u16 *hinH, *hinL; u16 *houtH, *houtL;
        if (s & 1) { hinH = h1hi; hinL = h1lo; houtH = h0hi; houtL = h0lo; }
        else       { hinH = h0hi; hinL = h0lo; houtH = h1hi; houtL = h1lo; }

        // ---- stage x_s tile (fp32 -> hi+lo), 512 threads
        {
            int row = tid >> 3, q = tid & 7;
            const float* xr = xenc + (size_t)(m0 + row) * 8064 + s * 63;
            #pragma unroll
            for (int ii = 0; ii < 8; ++ii) {
                int col = q * 8 + ii;
                float v = (col < 63) ? xr[col] : 0.f;
                u16 hh = f2b(v);
                XbH[row * 72 + col] = hh;
                XbL[row * 72 + col] = f2b(v - b2f(hh));
            }
        }
        // ---- stage this group's first chunk (index 2g)
        i4v stgH[6], stgL[6];
        #pragma unroll
        for (int i = 0; i < 6; ++i) {
            size_t off = (size_t)sgrow[i] * 1024 + (size_t)(2 * g) * 256 + sp16[i] * 8;
            stgH[i] = *(const i4v*)(WhhH + off);
            stgL[i] = *(const i4v*)(WhhL + off);
        }
        #pragma unroll
        for (int i = 0; i < 6; ++i) {
            *(i4v*)&WbH[g][srow[i] * 264 + sp16[i] * 8] = stgH[i];
            *(i4v*)&WbL[g][srow[i] * 264 + sp16[i] * 8] = stgL[i];
        }
        __syncthreads();

        f4v acc_r  = {0.f, 0.f, 0.f, 0.f};
        f4v acc_z  = {0.f, 0.f, 0.f, 0.f};
        f4v acc_gn = {0.f, 0.f, 0.f, 0.f};
        f4v acc_hn = {0.f, 0.f, 0.f, 0.f};

        // ---- gi (group 0 only): x @ Wih^T, K=64 padded, 3-term split
        if (g == 0) {
            #pragma unroll
            for (int ks = 0; ks < 2; ++ks) {
                int ao = ks * 32 + lk8 * 8;
                s8v ah = *(const s8v*)&XbH[(wv * 16 + lrow) * 72 + ao];
                s8v al = *(const s8v*)&XbL[(wv * 16 + lrow) * 72 + ao];
                s8v brh = *(const s8v*)&WisH[(lrow) * 72 + ao];
                s8v brl = *(const s8v*)&WisL[(lrow) * 72 + ao];
                s8v bzh = *(const s8v*)&WisH[(16 + lrow) * 72 + ao];
                s8v bzl = *(const s8v*)&WisL[(16 + lrow) * 72 + ao];
                s8v bnh = *(const s8v*)&WisH[(32 + lrow) * 72 + ao];
                s8v bnl = *(const s8v*)&WisL[(32 + lrow) * 72 + ao];
                acc_r  = mfma16(ah, brh, acc_r);
                acc_r  = mfma16(ah, brl, acc_r);
                acc_r  = mfma16(al, brh, acc_r);
                acc_z  = mfma16(ah, bzh, acc_z);
                acc_z  = mfma16(ah, bzl, acc_z);
                acc_z  = mfma16(al, bzh, acc_z);
                acc_gn = mfma16(ah, bnh, acc_gn);
                acc_gn = mfma16(ah, bnl, acc_gn);
                acc_gn = mfma16(al, bnh, acc_gn);
            }
        }

        const u16* hp = hinH + arow;
        const u16* lp = hinL + arow;

        // ---- prefetch second chunk (2g+1) into registers
        #pragma unroll
        for (int i = 0; i < 6; ++i) {
            size_t off = (size_t)sgrow[i] * 1024 + (size_t)(2 * g + 1) * 256 + sp16[i] * 8;
            stgH[i] = *(const i4v*)(WhhH + off);
            stgL[i] = *(const i4v*)(WhhL + off);
        }
        // ---- compute chunk 2g
        #pragma unroll
        for (int ks = 0; ks < 8; ++ks) {
            int kk = kbase + ks * 32;
            int bo = ks * 32 + lk8 * 8;
            s8v ahi = *(const s8v*)(hp + kk);
            s8v alo = *(const s8v*)(lp + kk);
            s8v brh = *(const s8v*)&WbH[g][(lrow) * 264 + bo];
            s8v brl = *(const s8v*)&WbL[g][(lrow) * 264 + bo];
            s8v bzh = *(const s8v*)&WbH[g][(16 + lrow) * 264 + bo];
            s8v bzl = *(const s8v*)&WbL[g][(16 + lrow) * 264 + bo];
            s8v bnh = *(const s8v*)&WbH[g][(32 + lrow) * 264 + bo];
            s8v bnl = *(const s8v*)&WbL[g][(32 + lrow) * 264 + bo];
            acc_r  = mfma16(ahi, brh, acc_r);
            acc_r  = mfma16(ahi, brl, acc_r);
            acc_r  = mfma16(alo, brh, acc_r);
            acc_z  = mfma16(ahi, bzh, acc_z);
            acc_z  = mfma16(ahi, bzl, acc_z);
            acc_z  = mfma16(alo, bzh, acc_z);
            acc_hn = mfma16(ahi, bnh, acc_hn);
            acc_hn = mfma16(ahi, bnl, acc_hn);
            acc_hn = mfma16(alo, bnh, acc_hn);
        }
        __syncthreads();
        #pragma unroll
        for (int i = 0; i < 6; ++i) {
            *(i4v*)&WbH[g][srow[i] * 264 + sp16[i] * 8] = stgH[i];
            *(i4v*)&WbL[g][srow[i] * 264 + sp16[i] * 8] = stgL[i];
        }
        __syncthreads();
        // ---- compute chunk 2g+1
        #pragma unroll
        for (int ks = 0; ks < 8; ++ks) {
            int kk = kbase + 256 + ks * 32;
            int bo = ks * 32 + lk8 * 8;
            s8v ahi = *(const s8v*)(hp + kk);
            s8v alo = *(const s8v*)(lp + kk);
            s8v brh = *(const s8v*)&WbH[g][(lrow) * 264 + bo];
            s8v brl = *(const s8v*)&WbL[g][(lrow) * 264 + bo];
            s8v bzh = *(const s8v*)&WbH[g][(16 + lrow) * 264 + bo];
            s8v bzl = *(const s8v*)&WbL[g][(16 + lrow) * 264 + bo];
            s8v bnh = *(const s8v*)&WbH[g][(32 + lrow) * 264 + bo];
            s8v bnl = *(const s8v*)&WbL[g][(32 + lrow) * 264 + bo];
            acc_r  = mfma16(ahi, brh, acc_r);
            acc_r  = mfma16(ahi, brl, acc_r);
            acc_r  = mfma16(alo, brh, acc_r);
            acc_z  = mfma16(ahi, bzh, acc_z);
            acc_z  = mfma16(ahi, bzl, acc_z);
            acc_z  = mfma16(alo, bzh, acc_z);
            acc_hn = mfma16(ahi, bnh, acc_hn);
            acc_hn = mfma16(ahi, bnl, acc_hn);
            acc_hn = mfma16(alo, bnh, acc_hn);
        }

        // ---- reduce k-group partials, gate epilogue (group 0)
        if (g == 1) {
            red[wv][0][lane] = acc_r;
            red[wv][1][lane] = acc_z;
            red[wv][2][lane] = acc_hn;
        }
        __syncthreads();
        if (g == 0) {
            f4v r1 = red[wv][0][lane];
            f4v z1 = red[wv][1][lane];
            f4v n1 = red[wv][2][lane];
            #pragma unroll
            for (int reg = 0; reg < 4; ++reg) {
                int brow = m0 + wv * 16 + lk8 * 4 + reg;
                float rr = sigf(acc_r[reg] + r1[reg] + bir + bhr);
                float zz = sigf(acc_z[reg] + z1[reg] + biz + bhz);
                float nn = tanhf(acc_gn[reg] + bin + rr * (acc_hn[reg] + n1[reg] + bhn));
                size_t off = (size_t)brow * 1024 + jcol;
                float hold = b2f(hinH[off]) + b2f(hinL[off]);
                float h = (1.f - zz) * nn + zz * hold;
                u16 hh = f2b(h);
                houtH[off] = hh;
                houtL[off] = f2b(h - b2f(hh));
            }
        }

        // ---- grid barrier (device-scope; L2 wb on release, inv on acquire)
        __syncthreads();
        if (tid == 0) {
            __threadfence();   // writeback this XCD's L2 (all block stores drained)
            int t = atomicAdd(cnt, 1);
            if (t == (int)gridDim.x - 1) {
                atomicExch(cnt, 0);
                __hip_atomic_store(flag, s + 1, __ATOMIC_RELEASE, __HIP_MEMORY_SCOPE_AGENT);
            } else {
                while (__hip_atomic_load(flag, __ATOMIC_ACQUIRE, __HIP_MEMORY_SCOPE_AGENT) < s + 1)
                    __builtin_amdgcn_s_sleep(2);
            }
        }
        __syncthreads();
        __threadfence();       // invalidate stale h in local caches
    }
}

// ---------------------------------------------------------------------------
// MODE 1 only: gh_dec = enc_h @ dec_Whh^T + dec_bhh (fp32 out).
template <int MODE>
__global__ __launch_bounds__(256, 1) void gru_gemm(
    const u16* __restrict__ WhhH, const u16* __restrict__ WhhL,
    const float* __restrict__ bhh,
    const u16* __restrict__ hin_hi, const u16* __restrict__ hin_lo,
    float* __restrict__ gh_out)
{
    __shared__ u16 WbH[48 * 264];
    __shared__ u16 WbL[48 * 264];

    const int tid  = threadIdx.x;
    const int lane = tid & 63;
    const int wave = tid >> 6;
    const int lrow = lane & 15;
    const int lk8  = lane >> 4;
    const int mt = blockIdx.x & 3;
    const int jt = blockIdx.x >> 2;
    const int m0 = mt * 64;
    const int j0 = jt * 16;

    f4v acc_r  = {0.f, 0.f, 0.f, 0.f};
    f4v acc_z  = {0.f, 0.f, 0.f, 0.f};
    f4v acc_hn = {0.f, 0.f, 0.f, 0.f};

    i4v stgH[6], stgL[6];
    #pragma unroll
    for (int i = 0; i < 6; ++i) {
        int c16 = i * 256 + tid;
        int row = c16 >> 5, p16 = c16 & 31;
        int grow = (row >> 4) * 1024 + j0 + (row & 15);
        size_t off = (size_t)grow * 1024 + p16 * 8;
        stgH[i] = *(const i4v*)(WhhH + off);
        stgL[i] = *(const i4v*)(WhhL + off);
    }
    #pragma unroll
    for (int i = 0; i < 6; ++i) {
        int c16 = i * 256 + tid;
        int row = c16 >> 5, p16 = c16 & 31;
        *(i4v*)&WbH[row * 264 + p16 * 8] = stgH[i];
        *(i4v*)&WbL[row * 264 + p16 * 8] = stgL[i];
    }
    __syncthreads();

    const size_t arow = (size_t)(m0 + wave * 16 + lrow) * 1024 + lk8 * 8;
    const u16* hp = hin_hi + arow;
    const u16* lp = hin_lo + arow;

    for (int c = 0; c < 4; ++c) {
        if (c < 3) {
            #pragma unroll
            for (int i = 0; i < 6; ++i) {
                int c16 = i * 256 + tid;
                int row = c16 >> 5, p16 = c16 & 31;
                int grow = (row >> 4) * 1024 + j0 + (row & 15);
                size_t off = (size_t)grow * 1024 + (c + 1) * 256 + p16 * 8;
                stgH[i] = *(const i4v*)(WhhH + off);
                stgL[i] = *(const i4v*)(WhhL + off);
            }
        }
        #pragma unroll
        for (int ks = 0; ks < 8; ++ks) {
            int kk = c * 256 + ks * 32;
            int bo = ks * 32 + lk8 * 8;
            s8v ahi = *(const s8v*)(hp + kk);
            s8v alo = *(const s8v*)(lp + kk);
            s8v brh = *(const s8v*)&WbH[(lrow) * 264 + bo];
            s8v brl = *(const s8v*)&WbL[(lrow) * 264 + bo];
            s8v bzh = *(const s8v*)&WbH[(16 + lrow) * 264 + bo];
            s8v bzl = *(const s8v*)&WbL[(16 + lrow) * 264 + bo];
            s8v bnh = *(const s8v*)&WbH[(32 + lrow) * 264 + bo];
            s8v bnl = *(const s8v*)&WbL[(32 + lrow) * 264 + bo];
            acc_r  = mfma16(ahi, brh, acc_r);
            acc_r  = mfma16(ahi, brl, acc_r);
            acc_r  = mfma16(alo, brh, acc_r);
            acc_z  = mfma16(ahi, bzh, acc_z);
            acc_z  = mfma16(ahi, bzl, acc_z);
            acc_z  = mfma16(alo, bzh, acc_z);
            acc_hn = mfma16(ahi, bnh, acc_hn);
            acc_hn = mfma16(ahi, bnl, acc_hn);
            acc_hn = mfma16(alo, bnh, acc_hn);
        }
        __syncthreads();
        if (c < 3) {
            #pragma unroll
            for (int i = 0; i < 6; ++i) {
                int c16 = i * 256 + tid;
                int row = c16 >> 5, p16 = c16 & 31;
                *(i4v*)&WbH[row * 264 + p16 * 8] = stgH[i];
                *(i4v*)&WbL[row * 264 + p16 * 8] = stgL[i];
            }
            __syncthreads();
        }
    }

    const int jcol = j0 + lrow;
    const float bhr = bhh[jcol];
    const float bhz = bhh[1024 + jcol];
    const float bhn = bhh[2048 + jcol];
    #pragma unroll
    for (int reg = 0; reg < 4; ++reg) {
        int brow = m0 + wave * 16 + lk8 * 4 + reg;
        gh_out[(size_t)brow * 3072 + jcol]        = acc_r[reg] + bhr;
        gh_out[(size_t)brow * 3072 + 1024 + jcol] = acc_z[reg] + bhz;
        gh_out[(size_t)brow * 3072 + 2048 + jcol] = acc_hn[reg] + bhn;
    }
}

// ---------------------------------------------------------------------------
// Fused decoder (unchanged from passing round)
__global__ __launch_bounds__(256, 1) void dec_fused(
    const u16* __restrict__ WihH, const u16* __restrict__ WihL,
    const float* __restrict__ bih,
    const float* __restrict__ xdec,
    const u16* __restrict__ ehi, const u16* __restrict__ elo,
    const float* __restrict__ gh,
    const u16* __restrict__ pWH, const u16* __restrict__ pWL,
    const float* __restrict__ pb,
    float* __restrict__ out)
{
    __shared__ u16 XdH[64 * 72];
    __shared__ u16 XdL[64 * 72];
    __shared__ u16 WiH_[192 * 72];
    __shared__ u16 WiL_[192 * 72];
    __shared__ u16 nsH[64 * 72];
    __shared__ u16 nsL[64 * 72];

    const int tid  = threadIdx.x;
    const int lane = tid & 63;
    const int wave = tid >> 6;
    const int lrow = lane & 15;
    const int lk8  = lane >> 4;
    const int b    = blockIdx.x;

    {
        int row = tid >> 2, q = tid & 3;
        const float* xr = xdec + (size_t)(b * 64 + row) * 63;
        #pragma unroll
        for (int ii = 0; ii < 16; ++ii) {
            int col = q * 16 + ii;
            float v = (col < 63) ? xr[col] : 0.f;
            u16 hh = f2b(v);
            XdH[row * 72 + col] = hh;
            XdL[row * 72 + col] = f2b(v - b2f(hh));
        }
    }

    f4v oacc[4];
    #pragma unroll
    for (int f = 0; f < 4; ++f) oacc[f] = f4v{0.f, 0.f, 0.f, 0.f};

    for (int j0 = 0; j0 < 1024; j0 += 64) {
        #pragma unroll
        for (int k = 0; k < 3; ++k) {
            int c = tid + k * 256;
            int r = c >> 2, qq = c & 3;
            int grow = (r >> 6) * 1024 + j0 + (r & 63);
            const u16* srcH = WihH + (size_t)grow * 64 + qq * 16;
            const u16* srcL = WihL + (size_t)grow * 64 + qq * 16;
            *(i4v*)&WiH_[r * 72 + qq * 16]     = *(const i4v*)srcH;
            *(i4v*)&WiH_[r * 72 + qq * 16 + 8] = *(const i4v*)(srcH + 8);
            *(i4v*)&WiL_[r * 72 + qq * 16]     = *(const i4v*)srcL;
            *(i4v*)&WiL_[r * 72 + qq * 16 + 8] = *(const i4v*)(srcL + 8);
        }
        __syncthreads();

        f4v ar[4], az[4], an[4];
        #pragma unroll
        for (int jf = 0; jf < 4; ++jf) {
            ar[jf] = f4v{0.f, 0.f, 0.f, 0.f};
            az[jf] = f4v{0.f, 0.f, 0.f, 0.f};
            an[jf] = f4v{0.f, 0.f, 0.f, 0.f};
        }
        #pragma unroll
        for (int ks = 0; ks < 2; ++ks) {
            int ao = ks * 32 + lk8 * 8;
            s8v ah = *(const s8v*)&XdH[(wave * 16 + lrow) * 72 + ao];
            s8v al = *(const s8v*)&XdL[(wave * 16 + lrow) * 72 + ao];
            #pragma unroll
            for (int jf = 0; jf < 4; ++jf) {
                s8v brh = *(const s8v*)&WiH_[(jf * 16 + lrow) * 72 + ao];
                s8v brl = *(const s8v*)&WiL_[(jf * 16 + lrow) * 72 + ao];
                s8v bzh = *(const s8v*)&WiH_[(64 + jf * 16 + lrow) * 72 + ao];
                s8v bzl = *(const s8v*)&WiL_[(64 + jf * 16 + lrow) * 72 + ao];
                s8v bnh = *(const s8v*)&WiH_[(128 + jf * 16 + lrow) * 72 + ao];
                s8v bnl = *(const s8v*)&WiL_[(128 + jf * 16 + lrow) * 72 + ao];
                ar[jf] = mfma16(ah, brh, ar[jf]);
                ar[jf] = mfma16(ah, brl, ar[jf]);
                ar[jf] = mfma16(al, brh, ar[jf]);
                az[jf] = mfma16(ah, bzh, az[jf]);
                az[jf] = mfma16(ah, bzl, az[jf]);
                az[jf] = mfma16(al, bzh, az[jf]);
                an[jf] = mfma16(ah, bnh, an[jf]);
                an[jf] = mfma16(ah, bnl, an[jf]);
                an[jf] = mfma16(al, bnh, an[jf]);
            }
        }

        #pragma unroll
        for (int jf = 0; jf < 4; ++jf) {
            int j = j0 + jf * 16 + lrow;
            float ghr = gh[(size_t)b * 3072 + j];
            float ghz = gh[(size_t)b * 3072 + 1024 + j];
            float ghn = gh[(size_t)b * 3072 + 2048 + j];
            float bir = bih[j];
            float biz = bih[1024 + j];
            float bin = bih[2048 + j];
            size_t eo = (size_t)b * 1024 + j;
            float he = b2f(ehi[eo]) + b2f(elo[eo]);
            #pragma unroll
            for (int reg = 0; reg < 4; ++reg) {
                float r  = sigf(ar[jf][reg] + bir + ghr);
                float z  = sigf(az[jf][reg] + biz + ghz);
                float nn = tanhf(an[jf][reg] + bin + r * ghn);
                float v  = (1.f - z) * nn + z * he;
                u16 hh = f2b(v);
                int lo_i = (wave * 16 + lk8 * 4 + reg) * 72 + jf * 16 + lrow;
                nsH[lo_i] = hh;
                nsL[lo_i] = f2b(v - b2f(hh));
            }
        }
        __syncthreads();

        #pragma unroll
        for (int ks = 0; ks < 2; ++ks) {
            int ao = ks * 32 + lk8 * 8;
            s8v ah = *(const s8v*)&nsH[(wave * 16 + lrow) * 72 + ao];
            s8v al = *(const s8v*)&nsL[(wave * 16 + lrow) * 72 + ao];
            #pragma unroll
            for (int f = 0; f < 4; ++f) {
                size_t bo = (size_t)(f * 16 + lrow) * 1024 + j0 + ks * 32 + lk8 * 8;
                s8v bh = *(const s8v*)(pWH + bo);
                s8v bl = *(const s8v*)(pWL + bo);
                oacc[f] = mfma16(ah, bh, oacc[f]);
                oacc[f] = mfma16(ah, bl, oacc[f]);
                oacc[f] = mfma16(al, bh, oacc[f]);
            }
        }
        __syncthreads();
    }

    #pragma unroll
    for (int f = 0; f < 4; ++f) {
        int o = f * 16 + lrow;
        if (o < 63) {
            float pbv = pb[o];
            #pragma unroll
            for (int reg = 0; reg < 4; ++reg) {
                int t = wave * 16 + lk8 * 4 + reg;
                out[((size_t)(b * 64 + t)) * 63 + o] = oacc[f][reg] + pbv;
            }
        }
    }
}

// ---------------------------------------------------------------------------
extern "C" void kernel_launch(void* const* d_in, const int* in_sizes, int n_in,
                              void* d_out, int out_size, void* d_ws, size_t ws_size,
                              hipStream_t stream)
{
    const float* enc_x = (const float*)d_in[0];
    const float* dec_x = (const float*)d_in[1];
    const float* eWih  = (const float*)d_in[2];
    const float* eWhh  = (const float*)d_in[3];
    const float* ebih  = (const float*)d_in[4];
    const float* ebhh  = (const float*)d_in[5];
    const float* dWih  = (const float*)d_in[6];
    const float* dWhh  = (const float*)d_in[7];
    const float* dbih  = (const float*)d_in[8];
    const float* dbhh  = (const float*)d_in[9];
    const float* pW    = (const float*)d_in[10];
    const float* pb    = (const float*)d_in[11];

    char* ws = (char*)d_ws;
    u16*   H0hi  = (u16*)(ws);                    // 512 KB (256 x 1024 bf16)
    u16*   H0lo  = (u16*)(ws + 524288);
    u16*   H1hi  = (u16*)(ws + 1048576);
    u16*   H1lo  = (u16*)(ws + 1572864);
    int*   bar   = (int*)(ws + 2097152);          // barrier: cnt, flag (+128 B)
    float* ghd   = (float*)(ws + 3145728);        // 3 MB (256 x 3072 fp32)
    u16*   eWhhH = (u16*)(ws + 6291456);          // 6 MB each
    u16*   eWhhL = (u16*)(ws + 12582912);
    u16*   dWhhH = (u16*)(ws + 18874368);
    u16*   dWhhL = (u16*)(ws + 25165824);
    u16*   eWihH = (u16*)(ws + 31457280);         // 384 KB each (3072 x 64)
    u16*   eWihL = (u16*)(ws + 31850496);
    u16*   dWihH = (u16*)(ws + 32243712);
    u16*   dWihL = (u16*)(ws + 32636928);
    u16*   pWH   = (u16*)(ws + 33030144);         // 128 KB each (64 x 1024)
    u16*   pWL   = (u16*)(ws + 33161216);

    // one-time fp32 -> bf16 hi+lo weight conversions
    conv_split<<<dim3(4096), dim3(256), 0, stream>>>(eWhh, eWhhH, eWhhL, 3145728);
    conv_split<<<dim3(4096), dim3(256), 0, stream>>>(dWhh, dWhhH, dWhhL, 3145728);
    conv_wih_split_pad<<<dim3(768), dim3(256), 0, stream>>>(eWih, eWihH, eWihL);
    conv_wih_split_pad<<<dim3(768), dim3(256), 0, stream>>>(dWih, dWihH, dWihL);
    conv_pw_split_pad<<<dim3(256), dim3(256), 0, stream>>>(pW, pWH, pWL);

    // zero h buffers (2 MB) + barrier words
    zero_ws<<<dim3(513), dim3(256), 0, stream>>>((i4v*)ws, 131080);

    // persistent encoder: all 128 steps, one launch
    enc_persist<<<dim3(256), dim3(512), 0, stream>>>(
        eWhhH, eWhhL, eWihH, eWihL, ebih, ebhh, enc_x,
        H0hi, H0lo, H1hi, H1lo, bar);
    // final enc_h lives in H0 (step 127 writes H0)

    // gh_dec = enc_h @ dec_Whh^T + dec_bhh
    gru_gemm<1><<<dim3(256), dim3(256), 0, stream>>>(
        dWhhH, dWhhL, dbhh, H0hi, H0lo, ghd);

    // fused decoder gates + projection -> fp32 out
    dec_fused<<<dim3(256), dim3(256), 0, stream>>>(
        dWihH, dWihL, dbih, dec_x, H0hi, H0lo, ghd, pWH, pWL, pb, (float*)d_out);
}

// Round 7
// 2954.271 us; speedup vs baseline: 2.7922x; 2.7922x over previous
//
#include <hip/hip_runtime.h>

// Seq2Seq GRU: B=256, S=128, T=64, I=63, H=1024. Inputs fp32, output fp32.
// All GEMMs: bf16 hi+lo 3-term split emulation (~fp32 accuracy).
// Encoder: ONE persistent kernel, 128 steps, device-atomic grid barrier.
//   Barrier protocol: relaxed polls (NO per-poll buffer_inv), single
//   release fence (wbl2) before arrive + single acquire fence (inv) after.
//   (fences via __builtin_amdgcn_fence — __hip_atomic_fence not in headers)

typedef unsigned short u16;
typedef __attribute__((ext_vector_type(8))) short s8v;   // 8 x bf16 (4 VGPRs)
typedef __attribute__((ext_vector_type(4))) float f4v;   // MFMA acc
typedef __attribute__((ext_vector_type(4))) int  i4v;    // 16B copy unit

__device__ __forceinline__ float b2f(u16 u) {
    return __uint_as_float(((unsigned int)u) << 16);
}
__device__ __forceinline__ u16 f2b(float f) {   // round-to-nearest-even
    unsigned int x = __float_as_uint(f);
    unsigned int r = x + 0x7fffu + ((x >> 16) & 1u);
    return (u16)(r >> 16);
}
__device__ __forceinline__ float sigf(float x) {
    return 1.0f / (1.0f + __expf(-x));
}
__device__ __forceinline__ f4v mfma16(s8v a, s8v b, f4v c) {
    return __builtin_amdgcn_mfma_f32_16x16x32_bf16(a, b, c, 0, 0, 0);
}

// ---------------------------------------------------------------------------
__global__ void zero_ws(i4v* __restrict__ p, int n) {
    int i = blockIdx.x * blockDim.x + threadIdx.x;
    if (i < n) { i4v z = {0, 0, 0, 0}; p[i] = z; }
}

__global__ void conv_split(const float* __restrict__ s, u16* __restrict__ hi,
                           u16* __restrict__ lo, int n) {
    int i = blockIdx.x * blockDim.x + threadIdx.x;
    int st = gridDim.x * blockDim.x;
    for (; i < n; i += st) {
        float v = s[i];
        u16 h = f2b(v);
        hi[i] = h;
        lo[i] = f2b(v - b2f(h));
    }
}

// Wih (3072 x 63 fp32) -> padded (3072 x 64) hi+lo, col 63 = 0
__global__ void conv_wih_split_pad(const float* __restrict__ s,
                                   u16* __restrict__ hi, u16* __restrict__ lo) {
    int idx = blockIdx.x * blockDim.x + threadIdx.x;
    int row = idx >> 6, col = idx & 63;
    float v = (col < 63) ? s[(size_t)row * 63 + col] : 0.f;
    u16 h = f2b(v);
    hi[idx] = h;
    lo[idx] = f2b(v - b2f(h));
}

// proj_W (63 x 1024 fp32) -> padded (64 x 1024) hi+lo, row 63 = 0
__global__ void conv_pw_split_pad(const float* __restrict__ s,
                                  u16* __restrict__ hi, u16* __restrict__ lo) {
    int idx = blockIdx.x * blockDim.x + threadIdx.x;
    float v = (idx < 63 * 1024) ? s[idx] : 0.f;
    u16 h = f2b(v);
    hi[idx] = h;
    lo[idx] = f2b(v - b2f(h));
}

// ---------------------------------------------------------------------------
// Persistent encoder: 128 GRU steps in one kernel, grid barrier between steps.
__global__ __launch_bounds__(512, 1) void enc_persist(
    const u16* __restrict__ WhhH, const u16* __restrict__ WhhL,
    const u16* __restrict__ WihH, const u16* __restrict__ WihL,
    const float* __restrict__ bih, const float* __restrict__ bhh,
    const float* __restrict__ xenc,
    u16* __restrict__ h0hi, u16* __restrict__ h0lo,
    u16* __restrict__ h1hi, u16* __restrict__ h1lo,
    int* __restrict__ bar)
{
    __shared__ u16 WbH[2][48 * 264];   // per-k-group Whh-hi chunk (BK=256,+8 pad)
    __shared__ u16 WbL[2][48 * 264];
    __shared__ u16 XbH[64 * 72];
    __shared__ u16 XbL[64 * 72];
    __shared__ u16 WisH[48 * 72];
    __shared__ u16 WisL[48 * 72];
    __shared__ f4v red[4][3][64];      // k-group-1 partial accs (r,z,hn)

    const int tid  = threadIdx.x;
    const int lane = tid & 63;
    const int wave = tid >> 6;          // 0..7
    const int g    = wave >> 2;         // k-group: 0 -> k[0,512), 1 -> k[512,1024)
    const int wv   = wave & 3;          // m-subtile (16 rows)
    const int gtid = tid & 255;         // thread id within k-group
    const int lrow = lane & 15;
    const int lk8  = lane >> 4;
    const int mt = blockIdx.x & 3;
    const int jt = blockIdx.x >> 2;
    const int m0 = mt * 64;
    const int j0 = jt * 16;

    // ---- one-time: Wih slice into LDS
    if (tid < 192) {
        int wr = tid >> 2, qq = tid & 3;
        int grow = (wr >> 4) * 1024 + j0 + (wr & 15);
        const u16* wpH = WihH + (size_t)grow * 64 + qq * 16;
        const u16* wpL = WihL + (size_t)grow * 64 + qq * 16;
        *(i4v*)&WisH[wr * 72 + qq * 16]     = *(const i4v*)wpH;
        *(i4v*)&WisH[wr * 72 + qq * 16 + 8] = *(const i4v*)(wpH + 8);
        *(i4v*)&WisL[wr * 72 + qq * 16]     = *(const i4v*)wpL;
        *(i4v*)&WisL[wr * 72 + qq * 16 + 8] = *(const i4v*)(wpL + 8);
    }

    const int jcol = j0 + lrow;
    const float bhr = bhh[jcol], bhz = bhh[1024 + jcol], bhn = bhh[2048 + jcol];
    const float bir = bih[jcol], biz = bih[1024 + jcol], bin = bih[2048 + jcol];

    // staging geometry (group-local, 256 threads cover 48x256 elements)
    int srow[6], sp16[6], sgrow[6];
    #pragma unroll
    for (int i = 0; i < 6; ++i) {
        int c16 = i * 256 + gtid;
        srow[i] = c16 >> 5;
        sp16[i] = c16 & 31;
        sgrow[i] = (srow[i] >> 4) * 1024 + j0 + (srow[i] & 15);
    }

    int* cnt  = bar;
    int* flag = bar + 64;   // 256 B away: separate cacheline from cnt

    const size_t arow = (size_t)(m0 + wv * 16 + lrow) * 1024 + lk8 * 8;
    const int kbase = g * 512;

    for (int s = 0; s < 128; ++s) {
        const u16 *hinH, *hinL; u16 *houtH, *houtL;
        if (s & 1) { hinH = h1hi; hinL = h1lo; houtH = h0hi; houtL = h0lo; }
        else       { hinH = h0hi; hinL = h0lo; houtH = h1hi; houtL = h1lo; }

        // ---- stage x_s tile (fp32 -> hi+lo), 512 threads
        {
            int row = tid >> 3, q = tid & 7;
            const float* xr = xenc + (size_t)(m0 + row) * 8064 + s * 63;
            #pragma unroll
            for (int ii = 0; ii < 8; ++ii) {
                int col = q * 8 + ii;
                float v = (col < 63) ? xr[col] : 0.f;
                u16 hh = f2b(v);
                XbH[row * 72 + col] = hh;
                XbL[row * 72 + col] = f2b(v - b2f(hh));
            }
        }
        // ---- stage this group's first chunk (index 2g)
        i4v stgH[6], stgL[6];
        #pragma unroll
        for (int i = 0; i < 6; ++i) {
            size_t off = (size_t)sgrow[i] * 1024 + (size_t)(2 * g) * 256 + sp16[i] * 8;
            stgH[i] = *(const i4v*)(WhhH + off);
            stgL[i] = *(const i4v*)(WhhL + off);
        }
        #pragma unroll
        for (int i = 0; i < 6; ++i) {
            *(i4v*)&WbH[g][srow[i] * 264 + sp16[i] * 8] = stgH[i];
            *(i4v*)&WbL[g][srow[i] * 264 + sp16[i] * 8] = stgL[i];
        }
        __syncthreads();

        f4v acc_r  = {0.f, 0.f, 0.f, 0.f};
        f4v acc_z  = {0.f, 0.f, 0.f, 0.f};
        f4v acc_gn = {0.f, 0.f, 0.f, 0.f};
        f4v acc_hn = {0.f, 0.f, 0.f, 0.f};

        // ---- gi (group 0 only): x @ Wih^T, K=64 padded, 3-term split
        if (g == 0) {
            #pragma unroll
            for (int ks = 0; ks < 2; ++ks) {
                int ao = ks * 32 + lk8 * 8;
                s8v ah = *(const s8v*)&XbH[(wv * 16 + lrow) * 72 + ao];
                s8v al = *(const s8v*)&XbL[(wv * 16 + lrow) * 72 + ao];
                s8v brh = *(const s8v*)&WisH[(lrow) * 72 + ao];
                s8v brl = *(const s8v*)&WisL[(lrow) * 72 + ao];
                s8v bzh = *(const s8v*)&WisH[(16 + lrow) * 72 + ao];
                s8v bzl = *(const s8v*)&WisL[(16 + lrow) * 72 + ao];
                s8v bnh = *(const s8v*)&WisH[(32 + lrow) * 72 + ao];
                s8v bnl = *(const s8v*)&WisL[(32 + lrow) * 72 + ao];
                acc_r  = mfma16(ah, brh, acc_r);
                acc_r  = mfma16(ah, brl, acc_r);
                acc_r  = mfma16(al, brh, acc_r);
                acc_z  = mfma16(ah, bzh, acc_z);
                acc_z  = mfma16(ah, bzl, acc_z);
                acc_z  = mfma16(al, bzh, acc_z);
                acc_gn = mfma16(ah, bnh, acc_gn);
                acc_gn = mfma16(ah, bnl, acc_gn);
                acc_gn = mfma16(al, bnh, acc_gn);
            }
        }

        const u16* hp = hinH + arow;
        const u16* lp = hinL + arow;

        // ---- prefetch second chunk (2g+1) into registers
        #pragma unroll
        for (int i = 0; i < 6; ++i) {
            size_t off = (size_t)sgrow[i] * 1024 + (size_t)(2 * g + 1) * 256 + sp16[i] * 8;
            stgH[i] = *(const i4v*)(WhhH + off);
            stgL[i] = *(const i4v*)(WhhL + off);
        }
        // ---- compute chunk 2g
        #pragma unroll
        for (int ks = 0; ks < 8; ++ks) {
            int kk = kbase + ks * 32;
            int bo = ks * 32 + lk8 * 8;
            s8v ahi = *(const s8v*)(hp + kk);
            s8v alo = *(const s8v*)(lp + kk);
            s8v brh = *(const s8v*)&WbH[g][(lrow) * 264 + bo];
            s8v brl = *(const s8v*)&WbL[g][(lrow) * 264 + bo];
            s8v bzh = *(const s8v*)&WbH[g][(16 + lrow) * 264 + bo];
            s8v bzl = *(const s8v*)&WbL[g][(16 + lrow) * 264 + bo];
            s8v bnh = *(const s8v*)&WbH[g][(32 + lrow) * 264 + bo];
            s8v bnl = *(const s8v*)&WbL[g][(32 + lrow) * 264 + bo];
            acc_r  = mfma16(ahi, brh, acc_r);
            acc_r  = mfma16(ahi, brl, acc_r);
            acc_r  = mfma16(alo, brh, acc_r);
            acc_z  = mfma16(ahi, bzh, acc_z);
            acc_z  = mfma16(ahi, bzl, acc_z);
            acc_z  = mfma16(alo, bzh, acc_z);
            acc_hn = mfma16(ahi, bnh, acc_hn);
            acc_hn = mfma16(ahi, bnl, acc_hn);
            acc_hn = mfma16(alo, bnh, acc_hn);
        }
        __syncthreads();
        #pragma unroll
        for (int i = 0; i < 6; ++i) {
            *(i4v*)&WbH[g][srow[i] * 264 + sp16[i] * 8] = stgH[i];
            *(i4v*)&WbL[g][srow[i] * 264 + sp16[i] * 8] = stgL[i];
        }
        __syncthreads();
        // ---- compute chunk 2g+1
        #pragma unroll
        for (int ks = 0; ks < 8; ++ks) {
            int kk = kbase + 256 + ks * 32;
            int bo = ks * 32 + lk8 * 8;
            s8v ahi = *(const s8v*)(hp + kk);
            s8v alo = *(const s8v*)(lp + kk);
            s8v brh = *(const s8v*)&WbH[g][(lrow) * 264 + bo];
            s8v brl = *(const s8v*)&WbL[g][(lrow) * 264 + bo];
            s8v bzh = *(const s8v*)&WbH[g][(16 + lrow) * 264 + bo];
            s8v bzl = *(const s8v*)&WbL[g][(16 + lrow) * 264 + bo];
            s8v bnh = *(const s8v*)&WbH[g][(32 + lrow) * 264 + bo];
            s8v bnl = *(const s8v*)&WbL[g][(32 + lrow) * 264 + bo];
            acc_r  = mfma16(ahi, brh, acc_r);
            acc_r  = mfma16(ahi, brl, acc_r);
            acc_r  = mfma16(alo, brh, acc_r);
            acc_z  = mfma16(ahi, bzh, acc_z);
            acc_z  = mfma16(ahi, bzl, acc_z);
            acc_z  = mfma16(alo, bzh, acc_z);
            acc_hn = mfma16(ahi, bnh, acc_hn);
            acc_hn = mfma16(ahi, bnl, acc_hn);
            acc_hn = mfma16(alo, bnh, acc_hn);
        }

        // ---- reduce k-group partials, gate epilogue (group 0)
        if (g == 1) {
            red[wv][0][lane] = acc_r;
            red[wv][1][lane] = acc_z;
            red[wv][2][lane] = acc_hn;
        }
        __syncthreads();
        if (g == 0) {
            f4v r1 = red[wv][0][lane];
            f4v z1 = red[wv][1][lane];
            f4v n1 = red[wv][2][lane];
            #pragma unroll
            for (int reg = 0; reg < 4; ++reg) {
                int brow = m0 + wv * 16 + lk8 * 4 + reg;
                float rr = sigf(acc_r[reg] + r1[reg] + bir + bhr);
                float zz = sigf(acc_z[reg] + z1[reg] + biz + bhz);
                float nn = tanhf(acc_gn[reg] + bin + rr * (acc_hn[reg] + n1[reg] + bhn));
                size_t off = (size_t)brow * 1024 + jcol;
                float hold = b2f(hinH[off]) + b2f(hinL[off]);
                float h = (1.f - zz) * nn + zz * hold;
                u16 hh = f2b(h);
                houtH[off] = hh;
                houtL[off] = f2b(h - b2f(hh));
            }
        }

        // ---- grid barrier: relaxed polls, one wbl2 (release) + one inv (acquire)
        __syncthreads();
        if (tid == 0) {
            __builtin_amdgcn_fence(__ATOMIC_RELEASE, "agent");
            int t = __hip_atomic_fetch_add(cnt, 1, __ATOMIC_RELAXED,
                                           __HIP_MEMORY_SCOPE_AGENT);
            int target = (s + 1) * 256;     // cumulative, never reset
            if (t == target - 1) {
                __hip_atomic_store(flag, target, __ATOMIC_RELAXED,
                                   __HIP_MEMORY_SCOPE_AGENT);
            } else {
                while (__hip_atomic_load(flag, __ATOMIC_RELAXED,
                                         __HIP_MEMORY_SCOPE_AGENT) < target)
                    __builtin_amdgcn_s_sleep(8);
            }
            __builtin_amdgcn_fence(__ATOMIC_ACQUIRE, "agent");
        }
        __syncthreads();
    }
}

// ---------------------------------------------------------------------------
// MODE 1 only: gh_dec = enc_h @ dec_Whh^T + dec_bhh (fp32 out).
template <int MODE>
__global__ __launch_bounds__(256, 1) void gru_gemm(
    const u16* __restrict__ WhhH, const u16* __restrict__ WhhL,
    const float* __restrict__ bhh,
    const u16* __restrict__ hin_hi, const u16* __restrict__ hin_lo,
    float* __restrict__ gh_out)
{
    __shared__ u16 WbH[48 * 264];
    __shared__ u16 WbL[48 * 264];

    const int tid  = threadIdx.x;
    const int lane = tid & 63;
    const int wave = tid >> 6;
    const int lrow = lane & 15;
    const int lk8  = lane >> 4;
    const int mt = blockIdx.x & 3;
    const int jt = blockIdx.x >> 2;
    const int m0 = mt * 64;
    const int j0 = jt * 16;

    f4v acc_r  = {0.f, 0.f, 0.f, 0.f};
    f4v acc_z  = {0.f, 0.f, 0.f, 0.f};
    f4v acc_hn = {0.f, 0.f, 0.f, 0.f};

    i4v stgH[6], stgL[6];
    #pragma unroll
    for (int i = 0; i < 6; ++i) {
        int c16 = i * 256 + tid;
        int row = c16 >> 5, p16 = c16 & 31;
        int grow = (row >> 4) * 1024 + j0 + (row & 15);
        size_t off = (size_t)grow * 1024 + p16 * 8;
        stgH[i] = *(const i4v*)(WhhH + off);
        stgL[i] = *(const i4v*)(WhhL + off);
    }
    #pragma unroll
    for (int i = 0; i < 6; ++i) {
        int c16 = i * 256 + tid;
        int row = c16 >> 5, p16 = c16 & 31;
        *(i4v*)&WbH[row * 264 + p16 * 8] = stgH[i];
        *(i4v*)&WbL[row * 264 + p16 * 8] = stgL[i];
    }
    __syncthreads();

    const size_t arow = (size_t)(m0 + wave * 16 + lrow) * 1024 + lk8 * 8;
    const u16* hp = hin_hi + arow;
    const u16* lp = hin_lo + arow;

    for (int c = 0; c < 4; ++c) {
        if (c < 3) {
            #pragma unroll
            for (int i = 0; i < 6; ++i) {
                int c16 = i * 256 + tid;
                int row = c16 >> 5, p16 = c16 & 31;
                int grow = (row >> 4) * 1024 + j0 + (row & 15);
                size_t off = (size_t)grow * 1024 + (c + 1) * 256 + p16 * 8;
                stgH[i] = *(const i4v*)(WhhH + off);
                stgL[i] = *(const i4v*)(WhhL + off);
            }
        }
        #pragma unroll
        for (int ks = 0; ks < 8; ++ks) {
            int kk = c * 256 + ks * 32;
            int bo = ks * 32 + lk8 * 8;
            s8v ahi = *(const s8v*)(hp + kk);
            s8v alo = *(const s8v*)(lp + kk);
            s8v brh = *(const s8v*)&WbH[(lrow) * 264 + bo];
            s8v brl = *(const s8v*)&WbL[(lrow) * 264 + bo];
            s8v bzh = *(const s8v*)&WbH[(16 + lrow) * 264 + bo];
            s8v bzl = *(const s8v*)&WbL[(16 + lrow) * 264 + bo];
            s8v bnh = *(const s8v*)&WbH[(32 + lrow) * 264 + bo];
            s8v bnl = *(const s8v*)&WbL[(32 + lrow) * 264 + bo];
            acc_r  = mfma16(ahi, brh, acc_r);
            acc_r  = mfma16(ahi, brl, acc_r);
            acc_r  = mfma16(alo, brh, acc_r);
            acc_z  = mfma16(ahi, bzh, acc_z);
            acc_z  = mfma16(ahi, bzl, acc_z);
            acc_z  = mfma16(alo, bzh, acc_z);
            acc_hn = mfma16(ahi, bnh, acc_hn);
            acc_hn = mfma16(ahi, bnl, acc_hn);
            acc_hn = mfma16(alo, bnh, acc_hn);
        }
        __syncthreads();
        if (c < 3) {
            #pragma unroll
            for (int i = 0; i < 6; ++i) {
                int c16 = i * 256 + tid;
                int row = c16 >> 5, p16 = c16 & 31;
                *(i4v*)&WbH[row * 264 + p16 * 8] = stgH[i];
                *(i4v*)&WbL[row * 264 + p16 * 8] = stgL[i];
            }
            __syncthreads();
        }
    }

    const int jcol = j0 + lrow;
    const float bhr = bhh[jcol];
    const float bhz = bhh[1024 + jcol];
    const float bhn = bhh[2048 + jcol];
    #pragma unroll
    for (int reg = 0; reg < 4; ++reg) {
        int brow = m0 + wave * 16 + lk8 * 4 + reg;
        gh_out[(size_t)brow * 3072 + jcol]        = acc_r[reg] + bhr;
        gh_out[(size_t)brow * 3072 + 1024 + jcol] = acc_z[reg] + bhz;
        gh_out[(size_t)brow * 3072 + 2048 + jcol] = acc_hn[reg] + bhn;
    }
}

// ---------------------------------------------------------------------------
// Fused decoder (unchanged from passing round)
__global__ __launch_bounds__(256, 1) void dec_fused(
    const u16* __restrict__ WihH, const u16* __restrict__ WihL,
    const float* __restrict__ bih,
    const float* __restrict__ xdec,
    const u16* __restrict__ ehi, const u16* __restrict__ elo,
    const float* __restrict__ gh,
    const u16* __restrict__ pWH, const u16* __restrict__ pWL,
    const float* __restrict__ pb,
    float* __restrict__ out)
{
    __shared__ u16 XdH[64 * 72];
    __shared__ u16 XdL[64 * 72];
    __shared__ u16 WiH_[192 * 72];
    __shared__ u16 WiL_[192 * 72];
    __shared__ u16 nsH[64 * 72];
    __shared__ u16 nsL[64 * 72];

    const int tid  = threadIdx.x;
    const int lane = tid & 63;
    const int wave = tid >> 6;
    const int lrow = lane & 15;
    const int lk8  = lane >> 4;
    const int b    = blockIdx.x;

    {
        int row = tid >> 2, q = tid & 3;
        const float* xr = xdec + (size_t)(b * 64 + row) * 63;
        #pragma unroll
        for (int ii = 0; ii < 16; ++ii) {
            int col = q * 16 + ii;
            float v = (col < 63) ? xr[col] : 0.f;
            u16 hh = f2b(v);
            XdH[row * 72 + col] = hh;
            XdL[row * 72 + col] = f2b(v - b2f(hh));
        }
    }

    f4v oacc[4];
    #pragma unroll
    for (int f = 0; f < 4; ++f) oacc[f] = f4v{0.f, 0.f, 0.f, 0.f};

    for (int j0 = 0; j0 < 1024; j0 += 64) {
        #pragma unroll
        for (int k = 0; k < 3; ++k) {
            int c = tid + k * 256;
            int r = c >> 2, qq = c & 3;
            int grow = (r >> 6) * 1024 + j0 + (r & 63);
            const u16* srcH = WihH + (size_t)grow * 64 + qq * 16;
            const u16* srcL = WihL + (size_t)grow * 64 + qq * 16;
            *(i4v*)&WiH_[r * 72 + qq * 16]     = *(const i4v*)srcH;
            *(i4v*)&WiH_[r * 72 + qq * 16 + 8] = *(const i4v*)(srcH + 8);
            *(i4v*)&WiL_[r * 72 + qq * 16]     = *(const i4v*)srcL;
            *(i4v*)&WiL_[r * 72 + qq * 16 + 8] = *(const i4v*)(srcL + 8);
        }
        __syncthreads();

        f4v ar[4], az[4], an[4];
        #pragma unroll
        for (int jf = 0; jf < 4; ++jf) {
            ar[jf] = f4v{0.f, 0.f, 0.f, 0.f};
            az[jf] = f4v{0.f, 0.f, 0.f, 0.f};
            an[jf] = f4v{0.f, 0.f, 0.f, 0.f};
        }
        #pragma unroll
        for (int ks = 0; ks < 2; ++ks) {
            int ao = ks * 32 + lk8 * 8;
            s8v ah = *(const s8v*)&XdH[(wave * 16 + lrow) * 72 + ao];
            s8v al = *(const s8v*)&XdL[(wave * 16 + lrow) * 72 + ao];
            #pragma unroll
            for (int jf = 0; jf < 4; ++jf) {
                s8v brh = *(const s8v*)&WiH_[(jf * 16 + lrow) * 72 + ao];
                s8v brl = *(const s8v*)&WiL_[(jf * 16 + lrow) * 72 + ao];
                s8v bzh = *(const s8v*)&WiH_[(64 + jf * 16 + lrow) * 72 + ao];
                s8v bzl = *(const s8v*)&WiL_[(64 + jf * 16 + lrow) * 72 + ao];
                s8v bnh = *(const s8v*)&WiH_[(128 + jf * 16 + lrow) * 72 + ao];
                s8v bnl = *(const s8v*)&WiL_[(128 + jf * 16 + lrow) * 72 + ao];
                ar[jf] = mfma16(ah, brh, ar[jf]);
                ar[jf] = mfma16(ah, brl, ar[jf]);
                ar[jf] = mfma16(al, brh, ar[jf]);
                az[jf] = mfma16(ah, bzh, az[jf]);
                az[jf] = mfma16(ah, bzl, az[jf]);
                az[jf] = mfma16(al, bzh, az[jf]);
                an[jf] = mfma16(ah, bnh, an[jf]);
                an[jf] = mfma16(ah, bnl, an[jf]);
                an[jf] = mfma16(al, bnh, an[jf]);
            }
        }

        #pragma unroll
        for (int jf = 0; jf < 4; ++jf) {
            int j = j0 + jf * 16 + lrow;
            float ghr = gh[(size_t)b * 3072 + j];
            float ghz = gh[(size_t)b * 3072 + 1024 + j];
            float ghn = gh[(size_t)b * 3072 + 2048 + j];
            float bir = bih[j];
            float biz = bih[1024 + j];
            float bin = bih[2048 + j];
            size_t eo = (size_t)b * 1024 + j;
            float he = b2f(ehi[eo]) + b2f(elo[eo]);
            #pragma unroll
            for (int reg = 0; reg < 4; ++reg) {
                float r  = sigf(ar[jf][reg] + bir + ghr);
                float z  = sigf(az[jf][reg] + biz + ghz);
                float nn = tanhf(an[jf][reg] + bin + r * ghn);
                float v  = (1.f - z) * nn + z * he;
                u16 hh = f2b(v);
                int lo_i = (wave * 16 + lk8 * 4 + reg) * 72 + jf * 16 + lrow;
                nsH[lo_i] = hh;
                nsL[lo_i] = f2b(v - b2f(hh));
            }
        }
        __syncthreads();

        #pragma unroll
        for (int ks = 0; ks < 2; ++ks) {
            int ao = ks * 32 + lk8 * 8;
            s8v ah = *(const s8v*)&nsH[(wave * 16 + lrow) * 72 + ao];
            s8v al = *(const s8v*)&nsL[(wave * 16 + lrow) * 72 + ao];
            #pragma unroll
            for (int f = 0; f < 4; ++f) {
                size_t bo = (size_t)(f * 16 + lrow) * 1024 + j0 + ks * 32 + lk8 * 8;
                s8v bh = *(const s8v*)(pWH + bo);
                s8v bl = *(const s8v*)(pWL + bo);
                oacc[f] = mfma16(ah, bh, oacc[f]);
                oacc[f] = mfma16(ah, bl, oacc[f]);
                oacc[f] = mfma16(al, bh, oacc[f]);
            }
        }
        __syncthreads();
    }

    #pragma unroll
    for (int f = 0; f < 4; ++f) {
        int o = f * 16 + lrow;
        if (o < 63) {
            float pbv = pb[o];
            #pragma unroll
            for (int reg = 0; reg < 4; ++reg) {
                int t = wave * 16 + lk8 * 4 + reg;
                out[((size_t)(b * 64 + t)) * 63 + o] = oacc[f][reg] + pbv;
            }
        }
    }
}

// ---------------------------------------------------------------------------
extern "C" void kernel_launch(void* const* d_in, const int* in_sizes, int n_in,
                              void* d_out, int out_size, void* d_ws, size_t ws_size,
                              hipStream_t stream)
{
    const float* enc_x = (const float*)d_in[0];
    const float* dec_x = (const float*)d_in[1];
    const float* eWih  = (const float*)d_in[2];
    const float* eWhh  = (const float*)d_in[3];
    const float* ebih  = (const float*)d_in[4];
    const float* ebhh  = (const float*)d_in[5];
    const float* dWih  = (const float*)d_in[6];
    const float* dWhh  = (const float*)d_in[7];
    const float* dbih  = (const float*)d_in[8];
    const float* dbhh  = (const float*)d_in[9];
    const float* pW    = (const float*)d_in[10];
    const float* pb    = (const float*)d_in[11];

    char* ws = (char*)d_ws;
    u16*   H0hi  = (u16*)(ws);                    // 512 KB (256 x 1024 bf16)
    u16*   H0lo  = (u16*)(ws + 524288);
    u16*   H1hi  = (u16*)(ws + 1048576);
    u16*   H1lo  = (u16*)(ws + 1572864);
    int*   bar   = (int*)(ws + 2097152);          // barrier: cnt @+0, flag @+256B
    float* ghd   = (float*)(ws + 3145728);        // 3 MB (256 x 3072 fp32)
    u16*   eWhhH = (u16*)(ws + 6291456);          // 6 MB each
    u16*   eWhhL = (u16*)(ws + 12582912);
    u16*   dWhhH = (u16*)(ws + 18874368);
    u16*   dWhhL = (u16*)(ws + 25165824);
    u16*   eWihH = (u16*)(ws + 31457280);         // 384 KB each (3072 x 64)
    u16*   eWihL = (u16*)(ws + 31850496);
    u16*   dWihH = (u16*)(ws + 32243712);
    u16*   dWihL = (u16*)(ws + 32636928);
    u16*   pWH   = (u16*)(ws + 33030144);         // 128 KB each (64 x 1024)
    u16*   pWL   = (u16*)(ws + 33161216);

    // one-time fp32 -> bf16 hi+lo weight conversions
    conv_split<<<dim3(4096), dim3(256), 0, stream>>>(eWhh, eWhhH, eWhhL, 3145728);
    conv_split<<<dim3(4096), dim3(256), 0, stream>>>(dWhh, dWhhH, dWhhL, 3145728);
    conv_wih_split_pad<<<dim3(768), dim3(256), 0, stream>>>(eWih, eWihH, eWihL);
    conv_wih_split_pad<<<dim3(768), dim3(256), 0, stream>>>(dWih, dWihH, dWihL);
    conv_pw_split_pad<<<dim3(256), dim3(256), 0, stream>>>(pW, pWH, pWL);

    // zero h buffers (2 MB) + barrier words (cnt @2 MB, flag @2 MB+256 B)
    zero_ws<<<dim3(513), dim3(256), 0, stream>>>((i4v*)ws, 131136);

    // persistent encoder: all 128 steps, one launch
    enc_persist<<<dim3(256), dim3(512), 0, stream>>>(
        eWhhH, eWhhL, eWihH, eWihL, ebih, ebhh, enc_x,
        H0hi, H0lo, H1hi, H1lo, bar);
    // final enc_h lives in H0 (step 127 writes H0)

    // gh_dec = enc_h @ dec_Whh^T + dec_bhh
    gru_gemm<1><<<dim3(256), dim3(256), 0, stream>>>(
        dWhhH, dWhhL, dbhh, H0hi, H0lo, ghd);

    // fused decoder gates + projection -> fp32 out
    dec_fused<<<dim3(256), dim3(256), 0, stream>>>(
        dWihH, dWihL, dbih, dec_x, H0hi, H0lo, ghd, pWH, pWL, pb, (float*)d_out);
}

// Round 8
// 2893.456 us; speedup vs baseline: 2.8509x; 1.0210x over previous
//
#include <hip/hip_runtime.h>

// Seq2Seq GRU: B=256, S=128, T=64, I=63, H=1024. Inputs fp32, output fp32.
// All GEMMs: bf16 hi+lo 3-term split emulation (~fp32 accuracy).
// Encoder: ONE persistent kernel, 128 steps.
// Barrier v3: 4 independent per-mt groups (recurrence is batch-row-local);
//   arrival = parallel epoch-slot store (no RMW contention); wait = one wave
//   polls 64 slots (one per lane) + __all. One wbl2 release + one inv acquire
//   per block per step (round-7-proven fence pattern).

typedef unsigned short u16;
typedef __attribute__((ext_vector_type(8))) short s8v;   // 8 x bf16 (4 VGPRs)
typedef __attribute__((ext_vector_type(4))) float f4v;   // MFMA acc
typedef __attribute__((ext_vector_type(4))) int  i4v;    // 16B copy unit

__device__ __forceinline__ float b2f(u16 u) {
    return __uint_as_float(((unsigned int)u) << 16);
}
__device__ __forceinline__ u16 f2b(float f) {   // round-to-nearest-even
    unsigned int x = __float_as_uint(f);
    unsigned int r = x + 0x7fffu + ((x >> 16) & 1u);
    return (u16)(r >> 16);
}
__device__ __forceinline__ float sigf(float x) {
    return 1.0f / (1.0f + __expf(-x));
}
__device__ __forceinline__ f4v mfma16(s8v a, s8v b, f4v c) {
    return __builtin_amdgcn_mfma_f32_16x16x32_bf16(a, b, c, 0, 0, 0);
}

// ---------------------------------------------------------------------------
__global__ void zero_ws(i4v* __restrict__ p, int n) {
    int i = blockIdx.x * blockDim.x + threadIdx.x;
    if (i < n) { i4v z = {0, 0, 0, 0}; p[i] = z; }
}

__global__ void conv_split(const float* __restrict__ s, u16* __restrict__ hi,
                           u16* __restrict__ lo, int n) {
    int i = blockIdx.x * blockDim.x + threadIdx.x;
    int st = gridDim.x * blockDim.x;
    for (; i < n; i += st) {
        float v = s[i];
        u16 h = f2b(v);
        hi[i] = h;
        lo[i] = f2b(v - b2f(h));
    }
}

// Wih (3072 x 63 fp32) -> padded (3072 x 64) hi+lo, col 63 = 0
__global__ void conv_wih_split_pad(const float* __restrict__ s,
                                   u16* __restrict__ hi, u16* __restrict__ lo) {
    int idx = blockIdx.x * blockDim.x + threadIdx.x;
    int row = idx >> 6, col = idx & 63;
    float v = (col < 63) ? s[(size_t)row * 63 + col] : 0.f;
    u16 h = f2b(v);
    hi[idx] = h;
    lo[idx] = f2b(v - b2f(h));
}

// proj_W (63 x 1024 fp32) -> padded (64 x 1024) hi+lo, row 63 = 0
__global__ void conv_pw_split_pad(const float* __restrict__ s,
                                  u16* __restrict__ hi, u16* __restrict__ lo) {
    int idx = blockIdx.x * blockDim.x + threadIdx.x;
    float v = (idx < 63 * 1024) ? s[idx] : 0.f;
    u16 h = f2b(v);
    hi[idx] = h;
    lo[idx] = f2b(v - b2f(h));
}

// ---------------------------------------------------------------------------
// Persistent encoder: 128 GRU steps in one kernel, per-mt-group barriers.
__global__ __launch_bounds__(512, 1) void enc_persist(
    const u16* __restrict__ WhhH, const u16* __restrict__ WhhL,
    const u16* __restrict__ WihH, const u16* __restrict__ WihL,
    const float* __restrict__ bih, const float* __restrict__ bhh,
    const float* __restrict__ xenc,
    u16* __restrict__ h0hi, u16* __restrict__ h0lo,
    u16* __restrict__ h1hi, u16* __restrict__ h1lo,
    int* __restrict__ ep)   // epoch slots: (mt*64 + jt) * 16 ints (64 B apart)
{
    __shared__ u16 WbH[2][48 * 264];   // per-k-group Whh-hi chunk (BK=256,+8 pad)
    __shared__ u16 WbL[2][48 * 264];
    __shared__ u16 XbH[64 * 72];
    __shared__ u16 XbL[64 * 72];
    __shared__ u16 WisH[48 * 72];
    __shared__ u16 WisL[48 * 72];
    __shared__ f4v red[4][3][64];      // k-group-1 partial accs (r,z,hn)

    const int tid  = threadIdx.x;
    const int lane = tid & 63;
    const int wave = tid >> 6;          // 0..7
    const int g    = wave >> 2;         // k-group: 0 -> k[0,512), 1 -> k[512,1024)
    const int wv   = wave & 3;          // m-subtile (16 rows)
    const int gtid = tid & 255;         // thread id within k-group
    const int lrow = lane & 15;
    const int lk8  = lane >> 4;
    const int mt = blockIdx.x & 3;
    const int jt = blockIdx.x >> 2;
    const int m0 = mt * 64;
    const int j0 = jt * 16;

    int* mySlot   = ep + (mt * 64 + jt) * 16;    // this block's epoch word
    int* laneSlot = ep + (mt * 64 + lane) * 16;  // wave-0 poll target

    // ---- one-time: Wih slice into LDS
    if (tid < 192) {
        int wr = tid >> 2, qq = tid & 3;
        int grow = (wr >> 4) * 1024 + j0 + (wr & 15);
        const u16* wpH = WihH + (size_t)grow * 64 + qq * 16;
        const u16* wpL = WihL + (size_t)grow * 64 + qq * 16;
        *(i4v*)&WisH[wr * 72 + qq * 16]     = *(const i4v*)wpH;
        *(i4v*)&WisH[wr * 72 + qq * 16 + 8] = *(const i4v*)(wpH + 8);
        *(i4v*)&WisL[wr * 72 + qq * 16]     = *(const i4v*)wpL;
        *(i4v*)&WisL[wr * 72 + qq * 16 + 8] = *(const i4v*)(wpL + 8);
    }

    const int jcol = j0 + lrow;
    const float bhr = bhh[jcol], bhz = bhh[1024 + jcol], bhn = bhh[2048 + jcol];
    const float bir = bih[jcol], biz = bih[1024 + jcol], bin = bih[2048 + jcol];

    // staging geometry (group-local, 256 threads cover 48x256 elements)
    int srow[6], sp16[6], sgrow[6];
    #pragma unroll
    for (int i = 0; i < 6; ++i) {
        int c16 = i * 256 + gtid;
        srow[i] = c16 >> 5;
        sp16[i] = c16 & 31;
        sgrow[i] = (srow[i] >> 4) * 1024 + j0 + (srow[i] & 15);
    }

    const size_t arow = (size_t)(m0 + wv * 16 + lrow) * 1024 + lk8 * 8;
    const int kbase = g * 512;

    for (int s = 0; s < 128; ++s) {
        const u16 *hinH, *hinL; u16 *houtH, *houtL;
        if (s & 1) { hinH = h1hi; hinL = h1lo; houtH = h0hi; houtL = h0lo; }
        else       { hinH = h0hi; hinL = h0lo; houtH = h1hi; houtL = h1lo; }

        // ---- stage x_s tile (fp32 -> hi+lo), 512 threads
        {
            int row = tid >> 3, q = tid & 7;
            const float* xr = xenc + (size_t)(m0 + row) * 8064 + s * 63;
            #pragma unroll
            for (int ii = 0; ii < 8; ++ii) {
                int col = q * 8 + ii;
                float v = (col < 63) ? xr[col] : 0.f;
                u16 hh = f2b(v);
                XbH[row * 72 + col] = hh;
                XbL[row * 72 + col] = f2b(v - b2f(hh));
            }
        }
        // ---- stage this group's first chunk (index 2g)
        i4v stgH[6], stgL[6];
        #pragma unroll
        for (int i = 0; i < 6; ++i) {
            size_t off = (size_t)sgrow[i] * 1024 + (size_t)(2 * g) * 256 + sp16[i] * 8;
            stgH[i] = *(const i4v*)(WhhH + off);
            stgL[i] = *(const i4v*)(WhhL + off);
        }
        #pragma unroll
        for (int i = 0; i < 6; ++i) {
            *(i4v*)&WbH[g][srow[i] * 264 + sp16[i] * 8] = stgH[i];
            *(i4v*)&WbL[g][srow[i] * 264 + sp16[i] * 8] = stgL[i];
        }
        __syncthreads();

        f4v acc_r  = {0.f, 0.f, 0.f, 0.f};
        f4v acc_z  = {0.f, 0.f, 0.f, 0.f};
        f4v acc_gn = {0.f, 0.f, 0.f, 0.f};
        f4v acc_hn = {0.f, 0.f, 0.f, 0.f};

        // ---- gi (group 0 only): x @ Wih^T, K=64 padded, 3-term split
        if (g == 0) {
            #pragma unroll
            for (int ks = 0; ks < 2; ++ks) {
                int ao = ks * 32 + lk8 * 8;
                s8v ah = *(const s8v*)&XbH[(wv * 16 + lrow) * 72 + ao];
                s8v al = *(const s8v*)&XbL[(wv * 16 + lrow) * 72 + ao];
                s8v brh = *(const s8v*)&WisH[(lrow) * 72 + ao];
                s8v brl = *(const s8v*)&WisL[(lrow) * 72 + ao];
                s8v bzh = *(const s8v*)&WisH[(16 + lrow) * 72 + ao];
                s8v bzl = *(const s8v*)&WisL[(16 + lrow) * 72 + ao];
                s8v bnh = *(const s8v*)&WisH[(32 + lrow) * 72 + ao];
                s8v bnl = *(const s8v*)&WisL[(32 + lrow) * 72 + ao];
                acc_r  = mfma16(ah, brh, acc_r);
                acc_r  = mfma16(ah, brl, acc_r);
                acc_r  = mfma16(al, brh, acc_r);
                acc_z  = mfma16(ah, bzh, acc_z);
                acc_z  = mfma16(ah, bzl, acc_z);
                acc_z  = mfma16(al, bzh, acc_z);
                acc_gn = mfma16(ah, bnh, acc_gn);
                acc_gn = mfma16(ah, bnl, acc_gn);
                acc_gn = mfma16(al, bnh, acc_gn);
            }
        }

        const u16* hp = hinH + arow;
        const u16* lp = hinL + arow;

        // ---- prefetch second chunk (2g+1) into registers
        #pragma unroll
        for (int i = 0; i < 6; ++i) {
            size_t off = (size_t)sgrow[i] * 1024 + (size_t)(2 * g + 1) * 256 + sp16[i] * 8;
            stgH[i] = *(const i4v*)(WhhH + off);
            stgL[i] = *(const i4v*)(WhhL + off);
        }
        // ---- compute chunk 2g
        #pragma unroll
        for (int ks = 0; ks < 8; ++ks) {
            int kk = kbase + ks * 32;
            int bo = ks * 32 + lk8 * 8;
            s8v ahi = *(const s8v*)(hp + kk);
            s8v alo = *(const s8v*)(lp + kk);
            s8v brh = *(const s8v*)&WbH[g][(lrow) * 264 + bo];
            s8v brl = *(const s8v*)&WbL[g][(lrow) * 264 + bo];
            s8v bzh = *(const s8v*)&WbH[g][(16 + lrow) * 264 + bo];
            s8v bzl = *(const s8v*)&WbL[g][(16 + lrow) * 264 + bo];
            s8v bnh = *(const s8v*)&WbH[g][(32 + lrow) * 264 + bo];
            s8v bnl = *(const s8v*)&WbL[g][(32 + lrow) * 264 + bo];
            acc_r  = mfma16(ahi, brh, acc_r);
            acc_r  = mfma16(ahi, brl, acc_r);
            acc_r  = mfma16(alo, brh, acc_r);
            acc_z  = mfma16(ahi, bzh, acc_z);
            acc_z  = mfma16(ahi, bzl, acc_z);
            acc_z  = mfma16(alo, bzh, acc_z);
            acc_hn = mfma16(ahi, bnh, acc_hn);
            acc_hn = mfma16(ahi, bnl, acc_hn);
            acc_hn = mfma16(alo, bnh, acc_hn);
        }
        __syncthreads();
        #pragma unroll
        for (int i = 0; i < 6; ++i) {
            *(i4v*)&WbH[g][srow[i] * 264 + sp16[i] * 8] = stgH[i];
            *(i4v*)&WbL[g][srow[i] * 264 + sp16[i] * 8] = stgL[i];
        }
        __syncthreads();
        // ---- compute chunk 2g+1
        #pragma unroll
        for (int ks = 0; ks < 8; ++ks) {
            int kk = kbase + 256 + ks * 32;
            int bo = ks * 32 + lk8 * 8;
            s8v ahi = *(const s8v*)(hp + kk);
            s8v alo = *(const s8v*)(lp + kk);
            s8v brh = *(const s8v*)&WbH[g][(lrow) * 264 + bo];
            s8v brl = *(const s8v*)&WbL[g][(lrow) * 264 + bo];
            s8v bzh = *(const s8v*)&WbH[g][(16 + lrow) * 264 + bo];
            s8v bzl = *(const s8v*)&WbL[g][(16 + lrow) * 264 + bo];
            s8v bnh = *(const s8v*)&WbH[g][(32 + lrow) * 264 + bo];
            s8v bnl = *(const s8v*)&WbL[g][(32 + lrow) * 264 + bo];
            acc_r  = mfma16(ahi, brh, acc_r);
            acc_r  = mfma16(ahi, brl, acc_r);
            acc_r  = mfma16(alo, brh, acc_r);
            acc_z  = mfma16(ahi, bzh, acc_z);
            acc_z  = mfma16(ahi, bzl, acc_z);
            acc_z  = mfma16(alo, bzh, acc_z);
            acc_hn = mfma16(ahi, bnh, acc_hn);
            acc_hn = mfma16(ahi, bnl, acc_hn);
            acc_hn = mfma16(alo, bnh, acc_hn);
        }

        // ---- reduce k-group partials, gate epilogue (group 0)
        if (g == 1) {
            red[wv][0][lane] = acc_r;
            red[wv][1][lane] = acc_z;
            red[wv][2][lane] = acc_hn;
        }
        __syncthreads();
        if (g == 0) {
            f4v r1 = red[wv][0][lane];
            f4v z1 = red[wv][1][lane];
            f4v n1 = red[wv][2][lane];
            #pragma unroll
            for (int reg = 0; reg < 4; ++reg) {
                int brow = m0 + wv * 16 + lk8 * 4 + reg;
                float rr = sigf(acc_r[reg] + r1[reg] + bir + bhr);
                float zz = sigf(acc_z[reg] + z1[reg] + biz + bhz);
                float nn = tanhf(acc_gn[reg] + bin + rr * (acc_hn[reg] + n1[reg] + bhn));
                size_t off = (size_t)brow * 1024 + jcol;
                float hold = b2f(hinH[off]) + b2f(hinL[off]);
                float h = (1.f - zz) * nn + zz * hold;
                u16 hh = f2b(h);
                houtH[off] = hh;
                houtL[off] = f2b(h - b2f(hh));
            }
        }

        // ---- per-mt-group barrier: slot store (no RMW) + wave-parallel poll
        __syncthreads();   // drains all h stores (vmcnt 0 at barrier)
        if (tid == 0) {
            __builtin_amdgcn_fence(__ATOMIC_RELEASE, "agent");   // wbl2
            __hip_atomic_store(mySlot, s + 1, __ATOMIC_RELAXED,
                               __HIP_MEMORY_SCOPE_AGENT);
        }
        if (wave == 0) {
            for (;;) {
                int v = __hip_atomic_load(laneSlot, __ATOMIC_RELAXED,
                                          __HIP_MEMORY_SCOPE_AGENT);
                if (__all(v >= s + 1)) break;
                __builtin_amdgcn_s_sleep(2);
            }
            __builtin_amdgcn_fence(__ATOMIC_ACQUIRE, "agent");   // inv L1/L2
        }
        __syncthreads();
    }
}

// ---------------------------------------------------------------------------
// gh_dec = enc_h @ dec_Whh^T + dec_bhh (fp32 out).
__global__ __launch_bounds__(256, 1) void gru_gemm1(
    const u16* __restrict__ WhhH, const u16* __restrict__ WhhL,
    const float* __restrict__ bhh,
    const u16* __restrict__ hin_hi, const u16* __restrict__ hin_lo,
    float* __restrict__ gh_out)
{
    __shared__ u16 WbH[48 * 264];
    __shared__ u16 WbL[48 * 264];

    const int tid  = threadIdx.x;
    const int lane = tid & 63;
    const int wave = tid >> 6;
    const int lrow = lane & 15;
    const int lk8  = lane >> 4;
    const int mt = blockIdx.x & 3;
    const int jt = blockIdx.x >> 2;
    const int m0 = mt * 64;
    const int j0 = jt * 16;

    f4v acc_r  = {0.f, 0.f, 0.f, 0.f};
    f4v acc_z  = {0.f, 0.f, 0.f, 0.f};
    f4v acc_hn = {0.f, 0.f, 0.f, 0.f};

    i4v stgH[6], stgL[6];
    #pragma unroll
    for (int i = 0; i < 6; ++i) {
        int c16 = i * 256 + tid;
        int row = c16 >> 5, p16 = c16 & 31;
        int grow = (row >> 4) * 1024 + j0 + (row & 15);
        size_t off = (size_t)grow * 1024 + p16 * 8;
        stgH[i] = *(const i4v*)(WhhH + off);
        stgL[i] = *(const i4v*)(WhhL + off);
    }
    #pragma unroll
    for (int i = 0; i < 6; ++i) {
        int c16 = i * 256 + tid;
        int row = c16 >> 5, p16 = c16 & 31;
        *(i4v*)&WbH[row * 264 + p16 * 8] = stgH[i];
        *(i4v*)&WbL[row * 264 + p16 * 8] = stgL[i];
    }
    __syncthreads();

    const size_t arow = (size_t)(m0 + wave * 16 + lrow) * 1024 + lk8 * 8;
    const u16* hp = hin_hi + arow;
    const u16* lp = hin_lo + arow;

    for (int c = 0; c < 4; ++c) {
        if (c < 3) {
            #pragma unroll
            for (int i = 0; i < 6; ++i) {
                int c16 = i * 256 + tid;
                int row = c16 >> 5, p16 = c16 & 31;
                int grow = (row >> 4) * 1024 + j0 + (row & 15);
                size_t off = (size_t)grow * 1024 + (c + 1) * 256 + p16 * 8;
                stgH[i] = *(const i4v*)(WhhH + off);
                stgL[i] = *(const i4v*)(WhhL + off);
            }
        }
        #pragma unroll
        for (int ks = 0; ks < 8; ++ks) {
            int kk = c * 256 + ks * 32;
            int bo = ks * 32 + lk8 * 8;
            s8v ahi = *(const s8v*)(hp + kk);
            s8v alo = *(const s8v*)(lp + kk);
            s8v brh = *(const s8v*)&WbH[(lrow) * 264 + bo];
            s8v brl = *(const s8v*)&WbL[(lrow) * 264 + bo];
            s8v bzh = *(const s8v*)&WbH[(16 + lrow) * 264 + bo];
            s8v bzl = *(const s8v*)&WbL[(16 + lrow) * 264 + bo];
            s8v bnh = *(const s8v*)&WbH[(32 + lrow) * 264 + bo];
            s8v bnl = *(const s8v*)&WbL[(32 + lrow) * 264 + bo];
            acc_r  = mfma16(ahi, brh, acc_r);
            acc_r  = mfma16(ahi, brl, acc_r);
            acc_r  = mfma16(alo, brh, acc_r);
            acc_z  = mfma16(ahi, bzh, acc_z);
            acc_z  = mfma16(ahi, bzl, acc_z);
            acc_z  = mfma16(alo, bzh, acc_z);
            acc_hn = mfma16(ahi, bnh, acc_hn);
            acc_hn = mfma16(ahi, bnl, acc_hn);
            acc_hn = mfma16(alo, bnh, acc_hn);
        }
        __syncthreads();
        if (c < 3) {
            #pragma unroll
            for (int i = 0; i < 6; ++i) {
                int c16 = i * 256 + tid;
                int row = c16 >> 5, p16 = c16 & 31;
                *(i4v*)&WbH[row * 264 + p16 * 8] = stgH[i];
                *(i4v*)&WbL[row * 264 + p16 * 8] = stgL[i];
            }
            __syncthreads();
        }
    }

    const int jcol = j0 + lrow;
    const float bhr = bhh[jcol];
    const float bhz = bhh[1024 + jcol];
    const float bhn = bhh[2048 + jcol];
    #pragma unroll
    for (int reg = 0; reg < 4; ++reg) {
        int brow = m0 + wave * 16 + lk8 * 4 + reg;
        gh_out[(size_t)brow * 3072 + jcol]        = acc_r[reg] + bhr;
        gh_out[(size_t)brow * 3072 + 1024 + jcol] = acc_z[reg] + bhz;
        gh_out[(size_t)brow * 3072 + 2048 + jcol] = acc_hn[reg] + bhn;
    }
}

// ---------------------------------------------------------------------------
// Fused decoder (unchanged from passing round)
__global__ __launch_bounds__(256, 1) void dec_fused(
    const u16* __restrict__ WihH, const u16* __restrict__ WihL,
    const float* __restrict__ bih,
    const float* __restrict__ xdec,
    const u16* __restrict__ ehi, const u16* __restrict__ elo,
    const float* __restrict__ gh,
    const u16* __restrict__ pWH, const u16* __restrict__ pWL,
    const float* __restrict__ pb,
    float* __restrict__ out)
{
    __shared__ u16 XdH[64 * 72];
    __shared__ u16 XdL[64 * 72];
    __shared__ u16 WiH_[192 * 72];
    __shared__ u16 WiL_[192 * 72];
    __shared__ u16 nsH[64 * 72];
    __shared__ u16 nsL[64 * 72];

    const int tid  = threadIdx.x;
    const int lane = tid & 63;
    const int wave = tid >> 6;
    const int lrow = lane & 15;
    const int lk8  = lane >> 4;
    const int b    = blockIdx.x;

    {
        int row = tid >> 2, q = tid & 3;
        const float* xr = xdec + (size_t)(b * 64 + row) * 63;
        #pragma unroll
        for (int ii = 0; ii < 16; ++ii) {
            int col = q * 16 + ii;
            float v = (col < 63) ? xr[col] : 0.f;
            u16 hh = f2b(v);
            XdH[row * 72 + col] = hh;
            XdL[row * 72 + col] = f2b(v - b2f(hh));
        }
    }

    f4v oacc[4];
    #pragma unroll
    for (int f = 0; f < 4; ++f) oacc[f] = f4v{0.f, 0.f, 0.f, 0.f};

    for (int j0 = 0; j0 < 1024; j0 += 64) {
        #pragma unroll
        for (int k = 0; k < 3; ++k) {
            int c = tid + k * 256;
            int r = c >> 2, qq = c & 3;
            int grow = (r >> 6) * 1024 + j0 + (r & 63);
            const u16* srcH = WihH + (size_t)grow * 64 + qq * 16;
            const u16* srcL = WihL + (size_t)grow * 64 + qq * 16;
            *(i4v*)&WiH_[r * 72 + qq * 16]     = *(const i4v*)srcH;
            *(i4v*)&WiH_[r * 72 + qq * 16 + 8] = *(const i4v*)(srcH + 8);
            *(i4v*)&WiL_[r * 72 + qq * 16]     = *(const i4v*)srcL;
            *(i4v*)&WiL_[r * 72 + qq * 16 + 8] = *(const i4v*)(srcL + 8);
        }
        __syncthreads();

        f4v ar[4], az[4], an[4];
        #pragma unroll
        for (int jf = 0; jf < 4; ++jf) {
            ar[jf] = f4v{0.f, 0.f, 0.f, 0.f};
            az[jf] = f4v{0.f, 0.f, 0.f, 0.f};
            an[jf] = f4v{0.f, 0.f, 0.f, 0.f};
        }
        #pragma unroll
        for (int ks = 0; ks < 2; ++ks) {
            int ao = ks * 32 + lk8 * 8;
            s8v ah = *(const s8v*)&XdH[(wave * 16 + lrow) * 72 + ao];
            s8v al = *(const s8v*)&XdL[(wave * 16 + lrow) * 72 + ao];
            #pragma unroll
            for (int jf = 0; jf < 4; ++jf) {
                s8v brh = *(const s8v*)&WiH_[(jf * 16 + lrow) * 72 + ao];
                s8v brl = *(const s8v*)&WiL_[(jf * 16 + lrow) * 72 + ao];
                s8v bzh = *(const s8v*)&WiH_[(64 + jf * 16 + lrow) * 72 + ao];
                s8v bzl = *(const s8v*)&WiL_[(64 + jf * 16 + lrow) * 72 + ao];
                s8v bnh = *(const s8v*)&WiH_[(128 + jf * 16 + lrow) * 72 + ao];
                s8v bnl = *(const s8v*)&WiL_[(128 + jf * 16 + lrow) * 72 + ao];
                ar[jf] = mfma16(ah, brh, ar[jf]);
                ar[jf] = mfma16(ah, brl, ar[jf]);
                ar[jf] = mfma16(al, brh, ar[jf]);
                az[jf] = mfma16(ah, bzh, az[jf]);
                az[jf] = mfma16(ah, bzl, az[jf]);
                az[jf] = mfma16(al, bzh, az[jf]);
                an[jf] = mfma16(ah, bnh, an[jf]);
                an[jf] = mfma16(ah, bnl, an[jf]);
                an[jf] = mfma16(al, bnh, an[jf]);
            }
        }

        #pragma unroll
        for (int jf = 0; jf < 4; ++jf) {
            int j = j0 + jf * 16 + lrow;
            float ghr = gh[(size_t)b * 3072 + j];
            float ghz = gh[(size_t)b * 3072 + 1024 + j];
            float ghn = gh[(size_t)b * 3072 + 2048 + j];
            float bir = bih[j];
            float biz = bih[1024 + j];
            float bin = bih[2048 + j];
            size_t eo = (size_t)b * 1024 + j;
            float he = b2f(ehi[eo]) + b2f(elo[eo]);
            #pragma unroll
            for (int reg = 0; reg < 4; ++reg) {
                float r  = sigf(ar[jf][reg] + bir + ghr);
                float z  = sigf(az[jf][reg] + biz + ghz);
                float nn = tanhf(an[jf][reg] + bin + r * ghn);
                float v  = (1.f - z) * nn + z * he;
                u16 hh = f2b(v);
                int lo_i = (wave * 16 + lk8 * 4 + reg) * 72 + jf * 16 + lrow;
                nsH[lo_i] = hh;
                nsL[lo_i] = f2b(v - b2f(hh));
            }
        }
        __syncthreads();

        #pragma unroll
        for (int ks = 0; ks < 2; ++ks) {
            int ao = ks * 32 + lk8 * 8;
            s8v ah = *(const s8v*)&nsH[(wave * 16 + lrow) * 72 + ao];
            s8v al = *(const s8v*)&nsL[(wave * 16 + lrow) * 72 + ao];
            #pragma unroll
            for (int f = 0; f < 4; ++f) {
                size_t bo = (size_t)(f * 16 + lrow) * 1024 + j0 + ks * 32 + lk8 * 8;
                s8v bh = *(const s8v*)(pWH + bo);
                s8v bl = *(const s8v*)(pWL + bo);
                oacc[f] = mfma16(ah, bh, oacc[f]);
                oacc[f] = mfma16(ah, bl, oacc[f]);
                oacc[f] = mfma16(al, bh, oacc[f]);
            }
        }
        __syncthreads();
    }

    #pragma unroll
    for (int f = 0; f < 4; ++f) {
        int o = f * 16 + lrow;
        if (o < 63) {
            float pbv = pb[o];
            #pragma unroll
            for (int reg = 0; reg < 4; ++reg) {
                int t = wave * 16 + lk8 * 4 + reg;
                out[((size_t)(b * 64 + t)) * 63 + o] = oacc[f][reg] + pbv;
            }
        }
    }
}

// ---------------------------------------------------------------------------
extern "C" void kernel_launch(void* const* d_in, const int* in_sizes, int n_in,
                              void* d_out, int out_size, void* d_ws, size_t ws_size,
                              hipStream_t stream)
{
    const float* enc_x = (const float*)d_in[0];
    const float* dec_x = (const float*)d_in[1];
    const float* eWih  = (const float*)d_in[2];
    const float* eWhh  = (const float*)d_in[3];
    const float* ebih  = (const float*)d_in[4];
    const float* ebhh  = (const float*)d_in[5];
    const float* dWih  = (const float*)d_in[6];
    const float* dWhh  = (const float*)d_in[7];
    const float* dbih  = (const float*)d_in[8];
    const float* dbhh  = (const float*)d_in[9];
    const float* pW    = (const float*)d_in[10];
    const float* pb    = (const float*)d_in[11];

    char* ws = (char*)d_ws;
    u16*   H0hi  = (u16*)(ws);                    // 512 KB (256 x 1024 bf16)
    u16*   H0lo  = (u16*)(ws + 524288);
    u16*   H1hi  = (u16*)(ws + 1048576);
    u16*   H1lo  = (u16*)(ws + 1572864);
    int*   ep    = (int*)(ws + 2097152);          // 256 epoch slots x 64 B = 16 KB
    float* ghd   = (float*)(ws + 3145728);        // 3 MB (256 x 3072 fp32)
    u16*   eWhhH = (u16*)(ws + 6291456);          // 6 MB each
    u16*   eWhhL = (u16*)(ws + 12582912);
    u16*   dWhhH = (u16*)(ws + 18874368);
    u16*   dWhhL = (u16*)(ws + 25165824);
    u16*   eWihH = (u16*)(ws + 31457280);         // 384 KB each (3072 x 64)
    u16*   eWihL = (u16*)(ws + 31850496);
    u16*   dWihH = (u16*)(ws + 32243712);
    u16*   dWihL = (u16*)(ws + 32636928);
    u16*   pWH   = (u16*)(ws + 33030144);         // 128 KB each (64 x 1024)
    u16*   pWL   = (u16*)(ws + 33161216);

    // one-time fp32 -> bf16 hi+lo weight conversions
    conv_split<<<dim3(4096), dim3(256), 0, stream>>>(eWhh, eWhhH, eWhhL, 3145728);
    conv_split<<<dim3(4096), dim3(256), 0, stream>>>(dWhh, dWhhH, dWhhL, 3145728);
    conv_wih_split_pad<<<dim3(768), dim3(256), 0, stream>>>(eWih, eWihH, eWihL);
    conv_wih_split_pad<<<dim3(768), dim3(256), 0, stream>>>(dWih, dWihH, dWihL);
    conv_pw_split_pad<<<dim3(256), dim3(256), 0, stream>>>(pW, pWH, pWL);

    // zero h buffers (2 MB) + epoch slots (16 KB)
    zero_ws<<<dim3(517), dim3(256), 0, stream>>>((i4v*)ws, 132096);

    // persistent encoder: all 128 steps, one launch
    enc_persist<<<dim3(256), dim3(512), 0, stream>>>(
        eWhhH, eWhhL, eWihH, eWihL, ebih, ebhh, enc_x,
        H0hi, H0lo, H1hi, H1lo, ep);
    // final enc_h lives in H0 (step 127 writes H0)

    // gh_dec = enc_h @ dec_Whh^T + dec_bhh
    gru_gemm1<<<dim3(256), dim3(256), 0, stream>>>(
        dWhhH, dWhhL, dbhh, H0hi, H0lo, ghd);

    // fused decoder gates + projection -> fp32 out
    dec_fused<<<dim3(256), dim3(256), 0, stream>>>(
        dWihH, dWihL, dbih, dec_x, H0hi, H0lo, ghd, pWH, pWL, pb, (float*)d_out);
}

// Round 9
// 2812.257 us; speedup vs baseline: 2.9332x; 1.0289x over previous
//
#include <hip/hip_runtime.h>

// Seq2Seq GRU: B=256, S=128, T=64, I=63, H=1024. Inputs fp32, output fp32.
// All GEMMs: bf16 hi+lo 3-term split emulation (~fp32 accuracy).
// Encoder: ONE persistent kernel, 128 steps, per-mt-group slot barrier.
// v4: FENCE-FREE coherence. h exchanged via relaxed agent-scope atomics
//   (bypass L1/L2 -> coherent by construction); Whh/x stay in warm L2
//   (no more per-step buffer_inv). XCD-aware block swizzle so same-jt
//   blocks share an XCD's L2 (per-XCD Whh footprint 1.6 MB < 4 MB L2).
//   h_prev carried in registers (no stale-cache read in epilogue).

typedef unsigned short u16;
typedef unsigned int   u32;
typedef unsigned long long u64;
typedef __attribute__((ext_vector_type(8))) short s8v;   // 8 x bf16 (4 VGPRs)
typedef __attribute__((ext_vector_type(4))) float f4v;   // MFMA acc
typedef __attribute__((ext_vector_type(4))) int  i4v;    // 16B copy unit

__device__ __forceinline__ float b2f(u16 u) {
    return __uint_as_float(((u32)u) << 16);
}
__device__ __forceinline__ u16 f2b(float f) {   // round-to-nearest-even
    u32 x = __float_as_uint(f);
    u32 r = x + 0x7fffu + ((x >> 16) & 1u);
    return (u16)(r >> 16);
}
__device__ __forceinline__ float sigf(float x) {
    return 1.0f / (1.0f + __expf(-x));
}
__device__ __forceinline__ f4v mfma16(s8v a, s8v b, f4v c) {
    return __builtin_amdgcn_mfma_f32_16x16x32_bf16(a, b, c, 0, 0, 0);
}
// coherent (agent-scope, cache-bypassing) 16B A-fragment load as 2 u64 atomics
__device__ __forceinline__ s8v loadA(const u16* p) {
    const u64* q = (const u64*)p;
    u64 a = __hip_atomic_load(q,     __ATOMIC_RELAXED, __HIP_MEMORY_SCOPE_AGENT);
    u64 b = __hip_atomic_load(q + 1, __ATOMIC_RELAXED, __HIP_MEMORY_SCOPE_AGENT);
    union { u64 u[2]; s8v v; } cv;
    cv.u[0] = a; cv.u[1] = b;
    return cv.v;
}

// ---------------------------------------------------------------------------
__global__ void zero_ws(i4v* __restrict__ p, int n) {
    int i = blockIdx.x * blockDim.x + threadIdx.x;
    if (i < n) { i4v z = {0, 0, 0, 0}; p[i] = z; }
}

__global__ void conv_split(const float* __restrict__ s, u16* __restrict__ hi,
                           u16* __restrict__ lo, int n) {
    int i = blockIdx.x * blockDim.x + threadIdx.x;
    int st = gridDim.x * blockDim.x;
    for (; i < n; i += st) {
        float v = s[i];
        u16 h = f2b(v);
        hi[i] = h;
        lo[i] = f2b(v - b2f(h));
    }
}

// Wih (3072 x 63 fp32) -> padded (3072 x 64) hi+lo, col 63 = 0
__global__ void conv_wih_split_pad(const float* __restrict__ s,
                                   u16* __restrict__ hi, u16* __restrict__ lo) {
    int idx = blockIdx.x * blockDim.x + threadIdx.x;
    int row = idx >> 6, col = idx & 63;
    float v = (col < 63) ? s[(size_t)row * 63 + col] : 0.f;
    u16 h = f2b(v);
    hi[idx] = h;
    lo[idx] = f2b(v - b2f(h));
}

// proj_W (63 x 1024 fp32) -> padded (64 x 1024) hi+lo, row 63 = 0
__global__ void conv_pw_split_pad(const float* __restrict__ s,
                                  u16* __restrict__ hi, u16* __restrict__ lo) {
    int idx = blockIdx.x * blockDim.x + threadIdx.x;
    float v = (idx < 63 * 1024) ? s[idx] : 0.f;
    u16 h = f2b(v);
    hi[idx] = h;
    lo[idx] = f2b(v - b2f(h));
}

// ---------------------------------------------------------------------------
// Persistent encoder: 128 GRU steps, per-mt-group slot barrier, fence-free.
__global__ __launch_bounds__(512, 1) void enc_persist(
    const u16* __restrict__ WhhH, const u16* __restrict__ WhhL,
    const u16* __restrict__ WihH, const u16* __restrict__ WihL,
    const float* __restrict__ bih, const float* __restrict__ bhh,
    const float* __restrict__ xenc,
    u16* __restrict__ h0hi, u16* __restrict__ h0lo,
    u16* __restrict__ h1hi, u16* __restrict__ h1lo,
    int* __restrict__ ep)   // epoch slots: (mt*64 + jt) * 16 ints (64 B apart)
{
    __shared__ u16 WbH[2][48 * 264];   // per-k-group Whh-hi chunk (BK=256,+8 pad)
    __shared__ u16 WbL[2][48 * 264];
    __shared__ u16 XbH[64 * 72];
    __shared__ u16 XbL[64 * 72];
    __shared__ u16 WisH[48 * 72];
    __shared__ u16 WisL[48 * 72];
    __shared__ f4v red[4][3][64];      // k-group-1 partial accs (r,z,hn)

    const int tid  = threadIdx.x;
    const int lane = tid & 63;
    const int wave = tid >> 6;          // 0..7
    const int g    = wave >> 2;         // k-group: 0 -> k[0,512), 1 -> k[512,1024)
    const int wv   = wave & 3;          // m-subtile (16 rows)
    const int gtid = tid & 255;         // thread id within k-group
    const int lrow = lane & 15;
    const int lk8  = lane >> 4;
    // XCD-aware swizzle: bid&7 = XCD (round-robin). Same-jt blocks co-XCD.
    const int bid = blockIdx.x;
    const int y   = bid >> 3;                  // 0..31
    const int mt  = y & 3;
    const int jt  = (bid & 7) * 8 + (y >> 2);  // 8 jt slices per XCD
    const int m0 = mt * 64;
    const int j0 = jt * 16;

    int* mySlot   = ep + (mt * 64 + jt) * 16;    // this block's epoch word
    int* laneSlot = ep + (mt * 64 + lane) * 16;  // wave-0 poll target

    // ---- one-time: Wih slice into LDS
    if (tid < 192) {
        int wr = tid >> 2, qq = tid & 3;
        int grow = (wr >> 4) * 1024 + j0 + (wr & 15);
        const u16* wpH = WihH + (size_t)grow * 64 + qq * 16;
        const u16* wpL = WihL + (size_t)grow * 64 + qq * 16;
        *(i4v*)&WisH[wr * 72 + qq * 16]     = *(const i4v*)wpH;
        *(i4v*)&WisH[wr * 72 + qq * 16 + 8] = *(const i4v*)(wpH + 8);
        *(i4v*)&WisL[wr * 72 + qq * 16]     = *(const i4v*)wpL;
        *(i4v*)&WisL[wr * 72 + qq * 16 + 8] = *(const i4v*)(wpL + 8);
    }

    const int jcol = j0 + lrow;
    const float bhr = bhh[jcol], bhz = bhh[1024 + jcol], bhn = bhh[2048 + jcol];
    const float bir = bih[jcol], biz = bih[1024 + jcol], bin = bih[2048 + jcol];

    // staging geometry (group-local, 256 threads cover 48x256 elements)
    int srow[6], sp16[6], sgrow[6];
    #pragma unroll
    for (int i = 0; i < 6; ++i) {
        int c16 = i * 256 + gtid;
        srow[i] = c16 >> 5;
        sp16[i] = c16 & 31;
        sgrow[i] = (srow[i] >> 4) * 1024 + j0 + (srow[i] & 15);
    }

    const size_t arow = (size_t)(m0 + wv * 16 + lrow) * 1024 + lk8 * 8;
    const int kbase = g * 512;

    float hprev[4] = {0.f, 0.f, 0.f, 0.f};   // this thread's own h values

    for (int s = 0; s < 128; ++s) {
        const u16 *hinH, *hinL; u16 *houtH, *houtL;
        if (s & 1) { hinH = h1hi; hinL = h1lo; houtH = h0hi; houtL = h0lo; }
        else       { hinH = h0hi; hinL = h0lo; houtH = h1hi; houtL = h1lo; }

        // ---- stage x_s tile (fp32 -> hi+lo), 512 threads (cached loads)
        {
            int row = tid >> 3, q = tid & 7;
            const float* xr = xenc + (size_t)(m0 + row) * 8064 + s * 63;
            #pragma unroll
            for (int ii = 0; ii < 8; ++ii) {
                int col = q * 8 + ii;
                float v = (col < 63) ? xr[col] : 0.f;
                u16 hh = f2b(v);
                XbH[row * 72 + col] = hh;
                XbL[row * 72 + col] = f2b(v - b2f(hh));
            }
        }
        // ---- stage this group's first chunk (index 2g) — cached (warm L2)
        i4v stgH[6], stgL[6];
        #pragma unroll
        for (int i = 0; i < 6; ++i) {
            size_t off = (size_t)sgrow[i] * 1024 + (size_t)(2 * g) * 256 + sp16[i] * 8;
            stgH[i] = *(const i4v*)(WhhH + off);
            stgL[i] = *(const i4v*)(WhhL + off);
        }
        #pragma unroll
        for (int i = 0; i < 6; ++i) {
            *(i4v*)&WbH[g][srow[i] * 264 + sp16[i] * 8] = stgH[i];
            *(i4v*)&WbL[g][srow[i] * 264 + sp16[i] * 8] = stgL[i];
        }
        __syncthreads();

        f4v acc_r  = {0.f, 0.f, 0.f, 0.f};
        f4v acc_z  = {0.f, 0.f, 0.f, 0.f};
        f4v acc_gn = {0.f, 0.f, 0.f, 0.f};
        f4v acc_hn = {0.f, 0.f, 0.f, 0.f};

        const u16* hp = hinH + arow;
        const u16* lp = hinL + arow;

        // ---- hoist chunk-2g A-fragment coherent loads (latency cover)
        s8v Ah[8], Al[8];
        #pragma unroll
        for (int ks = 0; ks < 8; ++ks) {
            int kk = kbase + ks * 32;
            Ah[ks] = loadA(hp + kk);
            Al[ks] = loadA(lp + kk);
        }

        // ---- gi (group 0 only): x @ Wih^T, K=64 padded, 3-term split
        if (g == 0) {
            #pragma unroll
            for (int ks = 0; ks < 2; ++ks) {
                int ao = ks * 32 + lk8 * 8;
                s8v ah = *(const s8v*)&XbH[(wv * 16 + lrow) * 72 + ao];
                s8v al = *(const s8v*)&XbL[(wv * 16 + lrow) * 72 + ao];
                s8v brh = *(const s8v*)&WisH[(lrow) * 72 + ao];
                s8v brl = *(const s8v*)&WisL[(lrow) * 72 + ao];
                s8v bzh = *(const s8v*)&WisH[(16 + lrow) * 72 + ao];
                s8v bzl = *(const s8v*)&WisL[(16 + lrow) * 72 + ao];
                s8v bnh = *(const s8v*)&WisH[(32 + lrow) * 72 + ao];
                s8v bnl = *(const s8v*)&WisL[(32 + lrow) * 72 + ao];
                acc_r  = mfma16(ah, brh, acc_r);
                acc_r  = mfma16(ah, brl, acc_r);
                acc_r  = mfma16(al, brh, acc_r);
                acc_z  = mfma16(ah, bzh, acc_z);
                acc_z  = mfma16(ah, bzl, acc_z);
                acc_z  = mfma16(al, bzh, acc_z);
                acc_gn = mfma16(ah, bnh, acc_gn);
                acc_gn = mfma16(ah, bnl, acc_gn);
                acc_gn = mfma16(al, bnh, acc_gn);
            }
        }

        // ---- prefetch second chunk (2g+1) Whh into registers (cached)
        #pragma unroll
        for (int i = 0; i < 6; ++i) {
            size_t off = (size_t)sgrow[i] * 1024 + (size_t)(2 * g + 1) * 256 + sp16[i] * 8;
            stgH[i] = *(const i4v*)(WhhH + off);
            stgL[i] = *(const i4v*)(WhhL + off);
        }
        // ---- compute chunk 2g
        #pragma unroll
        for (int ks = 0; ks < 8; ++ks) {
            int bo = ks * 32 + lk8 * 8;
            s8v ahi = Ah[ks];
            s8v alo = Al[ks];
            s8v brh = *(const s8v*)&WbH[g][(lrow) * 264 + bo];
            s8v brl = *(const s8v*)&WbL[g][(lrow) * 264 + bo];
            s8v bzh = *(const s8v*)&WbH[g][(16 + lrow) * 264 + bo];
            s8v bzl = *(const s8v*)&WbL[g][(16 + lrow) * 264 + bo];
            s8v bnh = *(const s8v*)&WbH[g][(32 + lrow) * 264 + bo];
            s8v bnl = *(const s8v*)&WbL[g][(32 + lrow) * 264 + bo];
            acc_r  = mfma16(ahi, brh, acc_r);
            acc_r  = mfma16(ahi, brl, acc_r);
            acc_r  = mfma16(alo, brh, acc_r);
            acc_z  = mfma16(ahi, bzh, acc_z);
            acc_z  = mfma16(ahi, bzl, acc_z);
            acc_z  = mfma16(alo, bzh, acc_z);
            acc_hn = mfma16(ahi, bnh, acc_hn);
            acc_hn = mfma16(ahi, bnl, acc_hn);
            acc_hn = mfma16(alo, bnh, acc_hn);
        }
        __syncthreads();
        #pragma unroll
        for (int i = 0; i < 6; ++i) {
            *(i4v*)&WbH[g][srow[i] * 264 + sp16[i] * 8] = stgH[i];
            *(i4v*)&WbL[g][srow[i] * 264 + sp16[i] * 8] = stgL[i];
        }
        // ---- hoist chunk-2g+1 A-fragment coherent loads
        #pragma unroll
        for (int ks = 0; ks < 8; ++ks) {
            int kk = kbase + 256 + ks * 32;
            Ah[ks] = loadA(hp + kk);
            Al[ks] = loadA(lp + kk);
        }
        __syncthreads();
        // ---- compute chunk 2g+1
        #pragma unroll
        for (int ks = 0; ks < 8; ++ks) {
            int bo = ks * 32 + lk8 * 8;
            s8v ahi = Ah[ks];
            s8v alo = Al[ks];
            s8v brh = *(const s8v*)&WbH[g][(lrow) * 264 + bo];
            s8v brl = *(const s8v*)&WbL[g][(lrow) * 264 + bo];
            s8v bzh = *(const s8v*)&WbH[g][(16 + lrow) * 264 + bo];
            s8v bzl = *(const s8v*)&WbL[g][(16 + lrow) * 264 + bo];
            s8v bnh = *(const s8v*)&WbH[g][(32 + lrow) * 264 + bo];
            s8v bnl = *(const s8v*)&WbL[g][(32 + lrow) * 264 + bo];
            acc_r  = mfma16(ahi, brh, acc_r);
            acc_r  = mfma16(ahi, brl, acc_r);
            acc_r  = mfma16(alo, brh, acc_r);
            acc_z  = mfma16(ahi, bzh, acc_z);
            acc_z  = mfma16(ahi, bzl, acc_z);
            acc_z  = mfma16(alo, bzh, acc_z);
            acc_hn = mfma16(ahi, bnh, acc_hn);
            acc_hn = mfma16(ahi, bnl, acc_hn);
            acc_hn = mfma16(alo, bnh, acc_hn);
        }

        // ---- reduce k-group partials, gate epilogue (group 0)
        if (g == 1) {
            red[wv][0][lane] = acc_r;
            red[wv][1][lane] = acc_z;
            red[wv][2][lane] = acc_hn;
        }
        __syncthreads();
        if (g == 0) {
            f4v r1 = red[wv][0][lane];
            f4v z1 = red[wv][1][lane];
            f4v n1 = red[wv][2][lane];
            #pragma unroll
            for (int reg = 0; reg < 4; ++reg) {
                int brow = m0 + wv * 16 + lk8 * 4 + reg;
                float rr = sigf(acc_r[reg] + r1[reg] + bir + bhr);
                float zz = sigf(acc_z[reg] + z1[reg] + biz + bhz);
                float nn = tanhf(acc_gn[reg] + bin + rr * (acc_hn[reg] + n1[reg] + bhn));
                float h = (1.f - zz) * nn + zz * hprev[reg];
                u16 hh = f2b(h);
                u16 ll = f2b(h - b2f(hh));
                hprev[reg] = b2f(hh) + b2f(ll);   // quantized carry (matches stores)
                // pack lane-pairs (consecutive jcol) into u32, coherent store
                u32 hiv = hh, lov = ll;
                u32 hin = (u32)__shfl_xor((int)hiv, 1, 64);
                u32 lon = (u32)__shfl_xor((int)lov, 1, 64);
                if ((lane & 1) == 0) {
                    size_t i32 = (size_t)brow * 512 + (jcol >> 1);
                    __hip_atomic_store((u32*)houtH + i32, hiv | (hin << 16),
                                       __ATOMIC_RELAXED, __HIP_MEMORY_SCOPE_AGENT);
                    __hip_atomic_store((u32*)houtL + i32, lov | (lon << 16),
                                       __ATOMIC_RELAXED, __HIP_MEMORY_SCOPE_AGENT);
                }
            }
        }

        // ---- per-mt-group barrier: slot store + wave-parallel poll (no fences:
        // h transport is coherent atomics; __syncthreads drains stores first)
        __syncthreads();
        if (tid == 0) {
            __hip_atomic_store(mySlot, s + 1, __ATOMIC_RELAXED,
                               __HIP_MEMORY_SCOPE_AGENT);
        }
        if (wave == 0) {
            for (;;) {
                int v = __hip_atomic_load(laneSlot, __ATOMIC_RELAXED,
                                          __HIP_MEMORY_SCOPE_AGENT);
                if (__all(v >= s + 1)) break;
                __builtin_amdgcn_s_sleep(2);
            }
        }
        __syncthreads();
    }
}

// ---------------------------------------------------------------------------
// gh_dec = enc_h @ dec_Whh^T + dec_bhh (fp32 out).
__global__ __launch_bounds__(256, 1) void gru_gemm1(
    const u16* __restrict__ WhhH, const u16* __restrict__ WhhL,
    const float* __restrict__ bhh,
    const u16* __restrict__ hin_hi, const u16* __restrict__ hin_lo,
    float* __restrict__ gh_out)
{
    __shared__ u16 WbH[48 * 264];
    __shared__ u16 WbL[48 * 264];

    const int tid  = threadIdx.x;
    const int lane = tid & 63;
    const int wave = tid >> 6;
    const int lrow = lane & 15;
    const int lk8  = lane >> 4;
    const int mt = blockIdx.x & 3;
    const int jt = blockIdx.x >> 2;
    const int m0 = mt * 64;
    const int j0 = jt * 16;

    f4v acc_r  = {0.f, 0.f, 0.f, 0.f};
    f4v acc_z  = {0.f, 0.f, 0.f, 0.f};
    f4v acc_hn = {0.f, 0.f, 0.f, 0.f};

    i4v stgH[6], stgL[6];
    #pragma unroll
    for (int i = 0; i < 6; ++i) {
        int c16 = i * 256 + tid;
        int row = c16 >> 5, p16 = c16 & 31;
        int grow = (row >> 4) * 1024 + j0 + (row & 15);
        size_t off = (size_t)grow * 1024 + p16 * 8;
        stgH[i] = *(const i4v*)(WhhH + off);
        stgL[i] = *(const i4v*)(WhhL + off);
    }
    #pragma unroll
    for (int i = 0; i < 6; ++i) {
        int c16 = i * 256 + tid;
        int row = c16 >> 5, p16 = c16 & 31;
        *(i4v*)&WbH[row * 264 + p16 * 8] = stgH[i];
        *(i4v*)&WbL[row * 264 + p16 * 8] = stgL[i];
    }
    __syncthreads();

    const size_t arow = (size_t)(m0 + wave * 16 + lrow) * 1024 + lk8 * 8;
    const u16* hp = hin_hi + arow;
    const u16* lp = hin_lo + arow;

    for (int c = 0; c < 4; ++c) {
        if (c < 3) {
            #pragma unroll
            for (int i = 0; i < 6; ++i) {
                int c16 = i * 256 + tid;
                int row = c16 >> 5, p16 = c16 & 31;
                int grow = (row >> 4) * 1024 + j0 + (row & 15);
                size_t off = (size_t)grow * 1024 + (c + 1) * 256 + p16 * 8;
                stgH[i] = *(const i4v*)(WhhH + off);
                stgL[i] = *(const i4v*)(WhhL + off);
            }
        }
        #pragma unroll
        for (int ks = 0; ks < 8; ++ks) {
            int kk = c * 256 + ks * 32;
            int bo = ks * 32 + lk8 * 8;
            s8v ahi = *(const s8v*)(hp + kk);
            s8v alo = *(const s8v*)(lp + kk);
            s8v brh = *(const s8v*)&WbH[(lrow) * 264 + bo];
            s8v brl = *(const s8v*)&WbL[(lrow) * 264 + bo];
            s8v bzh = *(const s8v*)&WbH[(16 + lrow) * 264 + bo];
            s8v bzl = *(const s8v*)&WbL[(16 + lrow) * 264 + bo];
            s8v bnh = *(const s8v*)&WbH[(32 + lrow) * 264 + bo];
            s8v bnl = *(const s8v*)&WbL[(32 + lrow) * 264 + bo];
            acc_r  = mfma16(ahi, brh, acc_r);
            acc_r  = mfma16(ahi, brl, acc_r);
            acc_r  = mfma16(alo, brh, acc_r);
            acc_z  = mfma16(ahi, bzh, acc_z);
            acc_z  = mfma16(ahi, bzl, acc_z);
            acc_z  = mfma16(alo, bzh, acc_z);
            acc_hn = mfma16(ahi, bnh, acc_hn);
            acc_hn = mfma16(ahi, bnl, acc_hn);
            acc_hn = mfma16(alo, bnh, acc_hn);
        }
        __syncthreads();
        if (c < 3) {
            #pragma unroll
            for (int i = 0; i < 6; ++i) {
                int c16 = i * 256 + tid;
                int row = c16 >> 5, p16 = c16 & 31;
                *(i4v*)&WbH[row * 264 + p16 * 8] = stgH[i];
                *(i4v*)&WbL[row * 264 + p16 * 8] = stgL[i];
            }
            __syncthreads();
        }
    }

    const int jcol = j0 + lrow;
    const float bhr = bhh[jcol];
    const float bhz = bhh[1024 + jcol];
    const float bhn = bhh[2048 + jcol];
    #pragma unroll
    for (int reg = 0; reg < 4; ++reg) {
        int brow = m0 + wave * 16 + lk8 * 4 + reg;
        gh_out[(size_t)brow * 3072 + jcol]        = acc_r[reg] + bhr;
        gh_out[(size_t)brow * 3072 + 1024 + jcol] = acc_z[reg] + bhz;
        gh_out[(size_t)brow * 3072 + 2048 + jcol] = acc_hn[reg] + bhn;
    }
}

// ---------------------------------------------------------------------------
// Fused decoder (unchanged from passing round)
__global__ __launch_bounds__(256, 1) void dec_fused(
    const u16* __restrict__ WihH, const u16* __restrict__ WihL,
    const float* __restrict__ bih,
    const float* __restrict__ xdec,
    const u16* __restrict__ ehi, const u16* __restrict__ elo,
    const float* __restrict__ gh,
    const u16* __restrict__ pWH, const u16* __restrict__ pWL,
    const float* __restrict__ pb,
    float* __restrict__ out)
{
    __shared__ u16 XdH[64 * 72];
    __shared__ u16 XdL[64 * 72];
    __shared__ u16 WiH_[192 * 72];
    __shared__ u16 WiL_[192 * 72];
    __shared__ u16 nsH[64 * 72];
    __shared__ u16 nsL[64 * 72];

    const int tid  = threadIdx.x;
    const int lane = tid & 63;
    const int wave = tid >> 6;
    const int lrow = lane & 15;
    const int lk8  = lane >> 4;
    const int b    = blockIdx.x;

    {
        int row = tid >> 2, q = tid & 3;
        const float* xr = xdec + (size_t)(b * 64 + row) * 63;
        #pragma unroll
        for (int ii = 0; ii < 16; ++ii) {
            int col = q * 16 + ii;
            float v = (col < 63) ? xr[col] : 0.f;
            u16 hh = f2b(v);
            XdH[row * 72 + col] = hh;
            XdL[row * 72 + col] = f2b(v - b2f(hh));
        }
    }

    f4v oacc[4];
    #pragma unroll
    for (int f = 0; f < 4; ++f) oacc[f] = f4v{0.f, 0.f, 0.f, 0.f};

    for (int j0 = 0; j0 < 1024; j0 += 64) {
        #pragma unroll
        for (int k = 0; k < 3; ++k) {
            int c = tid + k * 256;
            int r = c >> 2, qq = c & 3;
            int grow = (r >> 6) * 1024 + j0 + (r & 63);
            const u16* srcH = WihH + (size_t)grow * 64 + qq * 16;
            const u16* srcL = WihL + (size_t)grow * 64 + qq * 16;
            *(i4v*)&WiH_[r * 72 + qq * 16]     = *(const i4v*)srcH;
            *(i4v*)&WiH_[r * 72 + qq * 16 + 8] = *(const i4v*)(srcH + 8);
            *(i4v*)&WiL_[r * 72 + qq * 16]     = *(const i4v*)srcL;
            *(i4v*)&WiL_[r * 72 + qq * 16 + 8] = *(const i4v*)(srcL + 8);
        }
        __syncthreads();

        f4v ar[4], az[4], an[4];
        #pragma unroll
        for (int jf = 0; jf < 4; ++jf) {
            ar[jf] = f4v{0.f, 0.f, 0.f, 0.f};
            az[jf] = f4v{0.f, 0.f, 0.f, 0.f};
            an[jf] = f4v{0.f, 0.f, 0.f, 0.f};
        }
        #pragma unroll
        for (int ks = 0; ks < 2; ++ks) {
            int ao = ks * 32 + lk8 * 8;
            s8v ah = *(const s8v*)&XdH[(wave * 16 + lrow) * 72 + ao];
            s8v al = *(const s8v*)&XdL[(wave * 16 + lrow) * 72 + ao];
            #pragma unroll
            for (int jf = 0; jf < 4; ++jf) {
                s8v brh = *(const s8v*)&WiH_[(jf * 16 + lrow) * 72 + ao];
                s8v brl = *(const s8v*)&WiL_[(jf * 16 + lrow) * 72 + ao];
                s8v bzh = *(const s8v*)&WiH_[(64 + jf * 16 + lrow) * 72 + ao];
                s8v bzl = *(const s8v*)&WiL_[(64 + jf * 16 + lrow) * 72 + ao];
                s8v bnh = *(const s8v*)&WiH_[(128 + jf * 16 + lrow) * 72 + ao];
                s8v bnl = *(const s8v*)&WiL_[(128 + jf * 16 + lrow) * 72 + ao];
                ar[jf] = mfma16(ah, brh, ar[jf]);
                ar[jf] = mfma16(ah, brl, ar[jf]);
                ar[jf] = mfma16(al, brh, ar[jf]);
                az[jf] = mfma16(ah, bzh, az[jf]);
                az[jf] = mfma16(ah, bzl, az[jf]);
                az[jf] = mfma16(al, bzh, az[jf]);
                an[jf] = mfma16(ah, bnh, an[jf]);
                an[jf] = mfma16(ah, bnl, an[jf]);
                an[jf] = mfma16(al, bnh, an[jf]);
            }
        }

        #pragma unroll
        for (int jf = 0; jf < 4; ++jf) {
            int j = j0 + jf * 16 + lrow;
            float ghr = gh[(size_t)b * 3072 + j];
            float ghz = gh[(size_t)b * 3072 + 1024 + j];
            float ghn = gh[(size_t)b * 3072 + 2048 + j];
            float bir = bih[j];
            float biz = bih[1024 + j];
            float bin = bih[2048 + j];
            size_t eo = (size_t)b * 1024 + j;
            float he = b2f(ehi[eo]) + b2f(elo[eo]);
            #pragma unroll
            for (int reg = 0; reg < 4; ++reg) {
                float r  = sigf(ar[jf][reg] + bir + ghr);
                float z  = sigf(az[jf][reg] + biz + ghz);
                float nn = tanhf(an[jf][reg] + bin + r * ghn);
                float v  = (1.f - z) * nn + z * he;
                u16 hh = f2b(v);
                int lo_i = (wave * 16 + lk8 * 4 + reg) * 72 + jf * 16 + lrow;
                nsH[lo_i] = hh;
                nsL[lo_i] = f2b(v - b2f(hh));
            }
        }
        __syncthreads();

        #pragma unroll
        for (int ks = 0; ks < 2; ++ks) {
            int ao = ks * 32 + lk8 * 8;
            s8v ah = *(const s8v*)&nsH[(wave * 16 + lrow) * 72 + ao];
            s8v al = *(const s8v*)&nsL[(wave * 16 + lrow) * 72 + ao];
            #pragma unroll
            for (int f = 0; f < 4; ++f) {
                size_t bo = (size_t)(f * 16 + lrow) * 1024 + j0 + ks * 32 + lk8 * 8;
                s8v bh = *(const s8v*)(pWH + bo);
                s8v bl = *(const s8v*)(pWL + bo);
                oacc[f] = mfma16(ah, bh, oacc[f]);
                oacc[f] = mfma16(ah, bl, oacc[f]);
                oacc[f] = mfma16(al, bh, oacc[f]);
            }
        }
        __syncthreads();
    }

    #pragma unroll
    for (int f = 0; f < 4; ++f) {
        int o = f * 16 + lrow;
        if (o < 63) {
            float pbv = pb[o];
            #pragma unroll
            for (int reg = 0; reg < 4; ++reg) {
                int t = wave * 16 + lk8 * 4 + reg;
                out[((size_t)(b * 64 + t)) * 63 + o] = oacc[f][reg] + pbv;
            }
        }
    }
}

// ---------------------------------------------------------------------------
extern "C" void kernel_launch(void* const* d_in, const int* in_sizes, int n_in,
                              void* d_out, int out_size, void* d_ws, size_t ws_size,
                              hipStream_t stream)
{
    const float* enc_x = (const float*)d_in[0];
    const float* dec_x = (const float*)d_in[1];
    const float* eWih  = (const float*)d_in[2];
    const float* eWhh  = (const float*)d_in[3];
    const float* ebih  = (const float*)d_in[4];
    const float* ebhh  = (const float*)d_in[5];
    const float* dWih  = (const float*)d_in[6];
    const float* dWhh  = (const float*)d_in[7];
    const float* dbih  = (const float*)d_in[8];
    const float* dbhh  = (const float*)d_in[9];
    const float* pW    = (const float*)d_in[10];
    const float* pb    = (const float*)d_in[11];

    char* ws = (char*)d_ws;
    u16*   H0hi  = (u16*)(ws);                    // 512 KB (256 x 1024 bf16)
    u16*   H0lo  = (u16*)(ws + 524288);
    u16*   H1hi  = (u16*)(ws + 1048576);
    u16*   H1lo  = (u16*)(ws + 1572864);
    int*   ep    = (int*)(ws + 2097152);          // 256 epoch slots x 64 B = 16 KB
    float* ghd   = (float*)(ws + 3145728);        // 3 MB (256 x 3072 fp32)
    u16*   eWhhH = (u16*)(ws + 6291456);          // 6 MB each
    u16*   eWhhL = (u16*)(ws + 12582912);
    u16*   dWhhH = (u16*)(ws + 18874368);
    u16*   dWhhL = (u16*)(ws + 25165824);
    u16*   eWihH = (u16*)(ws + 31457280);         // 384 KB each (3072 x 64)
    u16*   eWihL = (u16*)(ws + 31850496);
    u16*   dWihH = (u16*)(ws + 32243712);
    u16*   dWihL = (u16*)(ws + 32636928);
    u16*   pWH   = (u16*)(ws + 33030144);         // 128 KB each (64 x 1024)
    u16*   pWL   = (u16*)(ws + 33161216);

    // one-time fp32 -> bf16 hi+lo weight conversions
    conv_split<<<dim3(4096), dim3(256), 0, stream>>>(eWhh, eWhhH, eWhhL, 3145728);
    conv_split<<<dim3(4096), dim3(256), 0, stream>>>(dWhh, dWhhH, dWhhL, 3145728);
    conv_wih_split_pad<<<dim3(768), dim3(256), 0, stream>>>(eWih, eWihH, eWihL);
    conv_wih_split_pad<<<dim3(768), dim3(256), 0, stream>>>(dWih, dWihH, dWihL);
    conv_pw_split_pad<<<dim3(256), dim3(256), 0, stream>>>(pW, pWH, pWL);

    // zero h buffers (2 MB) + epoch slots (16 KB)
    zero_ws<<<dim3(517), dim3(256), 0, stream>>>((i4v*)ws, 132096);

    // persistent encoder: all 128 steps, one launch
    enc_persist<<<dim3(256), dim3(512), 0, stream>>>(
        eWhhH, eWhhL, eWihH, eWihL, ebih, ebhh, enc_x,
        H0hi, H0lo, H1hi, H1lo, ep);
    // final enc_h lives in H0 (step 127 writes H0)

    // gh_dec = enc_h @ dec_Whh^T + dec_bhh
    gru_gemm1<<<dim3(256), dim3(256), 0, stream>>>(
        dWhhH, dWhhL, dbhh, H0hi, H0lo, ghd);

    // fused decoder gates + projection -> fp32 out
    dec_fused<<<dim3(256), dim3(256), 0, stream>>>(
        dWihH, dWihL, dbih, dec_x, H0hi, H0lo, ghd, pWH, pWL, pb, (float*)d_out);
}

// Round 10
// 2745.769 us; speedup vs baseline: 3.0043x; 1.0242x over previous
//
#include <hip/hip_runtime.h>

// Seq2Seq GRU: B=256, S=128, T=64, I=63, H=1024. Inputs fp32, output fp32.
// All GEMMs: bf16 hi+lo 3-term split emulation (~fp32 accuracy).
// Encoder v5: persistent kernel, 128 steps, per-mt-group slot barrier with
//   release(wbl2)/acquire(inv) fences (round-8-proven).
//   KEY CHANGE: Whh-hi (98 KB/block) lives in LDS for ALL 128 steps (immune
//   to the per-step L2 invalidate); only Whh-lo streams per step. x loaded
//   per-lane from global (no LDS tile). Next-step W-lo/x prefetched into
//   registers behind the barrier poll (immutable data needs no fencing).

typedef unsigned short u16;
typedef unsigned int   u32;
typedef __attribute__((ext_vector_type(8))) short s8v;   // 8 x bf16 (4 VGPRs)
typedef __attribute__((ext_vector_type(4))) float f4v;   // MFMA acc
typedef __attribute__((ext_vector_type(4))) int  i4v;    // 16B copy unit

__device__ __forceinline__ float b2f(u16 u) {
    return __uint_as_float(((u32)u) << 16);
}
__device__ __forceinline__ u16 f2b(float f) {   // round-to-nearest-even
    u32 x = __float_as_uint(f);
    u32 r = x + 0x7fffu + ((x >> 16) & 1u);
    return (u16)(r >> 16);
}
__device__ __forceinline__ float sigf(float x) {
    return 1.0f / (1.0f + __expf(-x));
}
__device__ __forceinline__ f4v mfma16(s8v a, s8v b, f4v c) {
    return __builtin_amdgcn_mfma_f32_16x16x32_bf16(a, b, c, 0, 0, 0);
}

// ---------------------------------------------------------------------------
__global__ void zero_ws(i4v* __restrict__ p, int n) {
    int i = blockIdx.x * blockDim.x + threadIdx.x;
    if (i < n) { i4v z = {0, 0, 0, 0}; p[i] = z; }
}

__global__ void conv_split(const float* __restrict__ s, u16* __restrict__ hi,
                           u16* __restrict__ lo, int n) {
    int i = blockIdx.x * blockDim.x + threadIdx.x;
    int st = gridDim.x * blockDim.x;
    for (; i < n; i += st) {
        float v = s[i];
        u16 h = f2b(v);
        hi[i] = h;
        lo[i] = f2b(v - b2f(h));
    }
}

// Wih (3072 x 63 fp32) -> padded (3072 x 64) hi+lo, col 63 = 0
__global__ void conv_wih_split_pad(const float* __restrict__ s,
                                   u16* __restrict__ hi, u16* __restrict__ lo) {
    int idx = blockIdx.x * blockDim.x + threadIdx.x;
    int row = idx >> 6, col = idx & 63;
    float v = (col < 63) ? s[(size_t)row * 63 + col] : 0.f;
    u16 h = f2b(v);
    hi[idx] = h;
    lo[idx] = f2b(v - b2f(h));
}

// proj_W (63 x 1024 fp32) -> padded (64 x 1024) hi+lo, row 63 = 0
__global__ void conv_pw_split_pad(const float* __restrict__ s,
                                  u16* __restrict__ hi, u16* __restrict__ lo) {
    int idx = blockIdx.x * blockDim.x + threadIdx.x;
    float v = (idx < 63 * 1024) ? s[idx] : 0.f;
    u16 h = f2b(v);
    hi[idx] = h;
    lo[idx] = f2b(v - b2f(h));
}

// ---------------------------------------------------------------------------
// Persistent encoder v5.
__global__ __launch_bounds__(512, 1) void enc_persist(
    const u16* __restrict__ WhhH, const u16* __restrict__ WhhL,
    const u16* __restrict__ WihH, const u16* __restrict__ WihL,
    const float* __restrict__ bih, const float* __restrict__ bhh,
    const float* __restrict__ xenc,
    u16* __restrict__ h0hi, u16* __restrict__ h0lo,
    u16* __restrict__ h1hi, u16* __restrict__ h1lo,
    int* __restrict__ ep)
{
    __shared__ u16 BH[48 * 1032];      // Whh-hi slice, PERSISTENT (99.1 KB)
    __shared__ u16 BLs[2][48 * 136];   // per-k-group Whh-lo chunk, BK=128 (25.5 KB)
    __shared__ u16 WisH[48 * 72];      // Wih slice (persistent)
    __shared__ u16 WisL[48 * 72];
    __shared__ f4v red[4][3][64];      // k-group-1 partials (12.3 KB)

    const int tid  = threadIdx.x;
    const int lane = tid & 63;
    const int wave = tid >> 6;          // 0..7
    const int g    = wave >> 2;         // k-group: 0 -> k[0,512), 1 -> k[512,1024)
    const int wv   = wave & 3;          // m-subtile (16 rows)
    const int gtid = tid & 255;
    const int lrow = lane & 15;
    const int lk8  = lane >> 4;
    // XCD-aware swizzle: bid&7 = XCD; XCD owns a 128-col j-range.
    const int bid = blockIdx.x;
    const int y   = bid >> 3;
    const int mt  = y & 3;
    const int jt  = (bid & 7) * 8 + (y >> 2);
    const int m0 = mt * 64;
    const int j0 = jt * 16;

    int* mySlot   = ep + (mt * 64 + jt) * 16;
    int* laneSlot = ep + (mt * 64 + lane) * 16;

    // ---- one-time: BH (Whh-hi) into LDS, 512 thr x 12 i4v
    #pragma unroll
    for (int i = 0; i < 12; ++i) {
        int u = i * 512 + tid;
        int row = u >> 7, p = u & 127;
        int grow = (row >> 4) * 1024 + j0 + (row & 15);
        *(i4v*)&BH[row * 1032 + p * 8] = *(const i4v*)(WhhH + (size_t)grow * 1024 + p * 8);
    }
    // ---- one-time: Wih slice into LDS
    if (tid < 192) {
        int wr = tid >> 2, qq = tid & 3;
        int grow = (wr >> 4) * 1024 + j0 + (wr & 15);
        const u16* wpH = WihH + (size_t)grow * 64 + qq * 16;
        const u16* wpL = WihL + (size_t)grow * 64 + qq * 16;
        *(i4v*)&WisH[wr * 72 + qq * 16]     = *(const i4v*)wpH;
        *(i4v*)&WisH[wr * 72 + qq * 16 + 8] = *(const i4v*)(wpH + 8);
        *(i4v*)&WisL[wr * 72 + qq * 16]     = *(const i4v*)wpL;
        *(i4v*)&WisL[wr * 72 + qq * 16 + 8] = *(const i4v*)(wpL + 8);
    }

    const int jcol = j0 + lrow;
    const float bhr = bhh[jcol], bhz = bhh[1024 + jcol], bhn = bhh[2048 + jcol];
    const float bir = bih[jcol], biz = bih[1024 + jcol], bin = bih[2048 + jcol];

    // BL staging geometry: per-group 256 threads cover 48x128 u16 = 3 i4v each
    int blrow[3], blp[3], blgrow[3];
    #pragma unroll
    for (int i = 0; i < 3; ++i) {
        int u = i * 256 + gtid;
        blrow[i] = u >> 4;
        blp[i]   = u & 15;
        blgrow[i] = (blrow[i] >> 4) * 1024 + j0 + (blrow[i] & 15);
    }

    const size_t arow = (size_t)(m0 + wv * 16 + lrow) * 1024 + lk8 * 8;
    const int kbase = g * 512;
    const float* xrow = xenc + (size_t)(m0 + wv * 16 + lrow) * 8064;

    float hprev[4] = {0.f, 0.f, 0.f, 0.f};

    // ---- initial prefetch: BL chunk 0 + x(s=0)
    i4v stgL[3];
    #pragma unroll
    for (int i = 0; i < 3; ++i)
        stgL[i] = *(const i4v*)(WhhL + (size_t)blgrow[i] * 1024 + kbase + blp[i] * 8);
    float xf[16];
    if (g == 0) {
        #pragma unroll
        for (int ks = 0; ks < 2; ++ks)
            #pragma unroll
            for (int j = 0; j < 8; ++j) {
                int col = ks * 32 + lk8 * 8 + j;
                xf[ks * 8 + j] = (col < 63) ? xrow[col] : 0.f;
            }
    }

    __syncthreads();   // BH / Wis ready

    for (int s = 0; s < 128; ++s) {
        const u16 *hinH, *hinL; u16 *houtH, *houtL;
        if (s & 1) { hinH = h1hi; hinL = h1lo; houtH = h0hi; houtL = h0lo; }
        else       { hinH = h0hi; hinL = h0lo; houtH = h1hi; houtL = h1lo; }

        // ---- write prefetched BL chunk 0
        #pragma unroll
        for (int i = 0; i < 3; ++i)
            *(i4v*)&BLs[g][blrow[i] * 136 + blp[i] * 8] = stgL[i];
        __syncthreads();

        f4v acc_r  = {0.f, 0.f, 0.f, 0.f};
        f4v acc_z  = {0.f, 0.f, 0.f, 0.f};
        f4v acc_gn = {0.f, 0.f, 0.f, 0.f};
        f4v acc_hn = {0.f, 0.f, 0.f, 0.f};

        // ---- gi (group 0): x @ Wih^T, K=64 padded, 3-term split
        if (g == 0) {
            #pragma unroll
            for (int ks = 0; ks < 2; ++ks) {
                union { u16 a[8]; s8v v; } xh, xl;
                #pragma unroll
                for (int j = 0; j < 8; ++j) {
                    float v = xf[ks * 8 + j];
                    u16 hh = f2b(v);
                    xh.a[j] = hh;
                    xl.a[j] = f2b(v - b2f(hh));
                }
                int ao = ks * 32 + lk8 * 8;
                s8v brh = *(const s8v*)&WisH[(lrow) * 72 + ao];
                s8v brl = *(const s8v*)&WisL[(lrow) * 72 + ao];
                s8v bzh = *(const s8v*)&WisH[(16 + lrow) * 72 + ao];
                s8v bzl = *(const s8v*)&WisL[(16 + lrow) * 72 + ao];
                s8v bnh = *(const s8v*)&WisH[(32 + lrow) * 72 + ao];
                s8v bnl = *(const s8v*)&WisL[(32 + lrow) * 72 + ao];
                acc_r  = mfma16(xh.v, brh, acc_r);
                acc_r  = mfma16(xh.v, brl, acc_r);
                acc_r  = mfma16(xl.v, brh, acc_r);
                acc_z  = mfma16(xh.v, bzh, acc_z);
                acc_z  = mfma16(xh.v, bzl, acc_z);
                acc_z  = mfma16(xl.v, bzh, acc_z);
                acc_gn = mfma16(xh.v, bnh, acc_gn);
                acc_gn = mfma16(xh.v, bnl, acc_gn);
                acc_gn = mfma16(xl.v, bnh, acc_gn);
            }
        }

        const u16* hp = hinH + arow;
        const u16* lp = hinL + arow;

        // ---- K loop: 4 chunks of BK=128 per k-group
        for (int c = 0; c < 4; ++c) {
            if (c < 3) {   // prefetch next BL chunk into regs
                #pragma unroll
                for (int i = 0; i < 3; ++i)
                    stgL[i] = *(const i4v*)(WhhL + (size_t)blgrow[i] * 1024 +
                                            kbase + (c + 1) * 128 + blp[i] * 8);
            }
            #pragma unroll
            for (int ks = 0; ks < 4; ++ks) {
                int kk = kbase + c * 128 + ks * 32;
                int bh = kk + lk8 * 8;            // BH col (absolute k)
                int bl = ks * 32 + lk8 * 8;       // BL col (chunk-local)
                s8v ahi = *(const s8v*)(hp + kk);
                s8v alo = *(const s8v*)(lp + kk);
                s8v brh = *(const s8v*)&BH[(lrow) * 1032 + bh];
                s8v brl = *(const s8v*)&BLs[g][(lrow) * 136 + bl];
                s8v bzh = *(const s8v*)&BH[(16 + lrow) * 1032 + bh];
                s8v bzl = *(const s8v*)&BLs[g][(16 + lrow) * 136 + bl];
                s8v bnh = *(const s8v*)&BH[(32 + lrow) * 1032 + bh];
                s8v bnl = *(const s8v*)&BLs[g][(32 + lrow) * 136 + bl];
                acc_r  = mfma16(ahi, brh, acc_r);
                acc_r  = mfma16(ahi, brl, acc_r);
                acc_r  = mfma16(alo, brh, acc_r);
                acc_z  = mfma16(ahi, bzh, acc_z);
                acc_z  = mfma16(ahi, bzl, acc_z);
                acc_z  = mfma16(alo, bzh, acc_z);
                acc_hn = mfma16(ahi, bnh, acc_hn);
                acc_hn = mfma16(ahi, bnl, acc_hn);
                acc_hn = mfma16(alo, bnh, acc_hn);
            }
            __syncthreads();
            if (c < 3) {
                #pragma unroll
                for (int i = 0; i < 3; ++i)
                    *(i4v*)&BLs[g][blrow[i] * 136 + blp[i] * 8] = stgL[i];
                __syncthreads();
            }
        }

        // ---- reduce k-group partials, gate epilogue (group 0)
        if (g == 1) {
            red[wv][0][lane] = acc_r;
            red[wv][1][lane] = acc_z;
            red[wv][2][lane] = acc_hn;
        }
        __syncthreads();
        if (g == 0) {
            f4v r1 = red[wv][0][lane];
            f4v z1 = red[wv][1][lane];
            f4v n1 = red[wv][2][lane];
            #pragma unroll
            for (int reg = 0; reg < 4; ++reg) {
                int brow = m0 + wv * 16 + lk8 * 4 + reg;
                float rr = sigf(acc_r[reg] + r1[reg] + bir + bhr);
                float zz = sigf(acc_z[reg] + z1[reg] + biz + bhz);
                float nn = tanhf(acc_gn[reg] + bin + rr * (acc_hn[reg] + n1[reg] + bhn));
                float h = (1.f - zz) * nn + zz * hprev[reg];
                u16 hh = f2b(h);
                u16 ll = f2b(h - b2f(hh));
                hprev[reg] = b2f(hh) + b2f(ll);
                size_t off = (size_t)brow * 1024 + jcol;
                houtH[off] = hh;
                houtL[off] = ll;
            }
        }

        // ---- barrier: release fence + slot store; prefetch behind poll; acquire
        __syncthreads();   // drains h stores (vmcnt 0)
        if (tid == 0) {
            __builtin_amdgcn_fence(__ATOMIC_RELEASE, "agent");   // wbl2
            __hip_atomic_store(mySlot, s + 1, __ATOMIC_RELAXED,
                               __HIP_MEMORY_SCOPE_AGENT);
        }
        // prefetch next step's BL chunk0 + x (immutable: no fence ordering needed)
        #pragma unroll
        for (int i = 0; i < 3; ++i)
            stgL[i] = *(const i4v*)(WhhL + (size_t)blgrow[i] * 1024 + kbase + blp[i] * 8);
        if (g == 0) {
            int sn = (s < 127) ? s + 1 : 127;
            const float* xr = xrow + sn * 63;
            #pragma unroll
            for (int ks = 0; ks < 2; ++ks)
                #pragma unroll
                for (int j = 0; j < 8; ++j) {
                    int col = ks * 32 + lk8 * 8 + j;
                    xf[ks * 8 + j] = (col < 63) ? xr[col] : 0.f;
                }
        }
        if (wave == 0) {
            for (;;) {
                int v = __hip_atomic_load(laneSlot, __ATOMIC_RELAXED,
                                          __HIP_MEMORY_SCOPE_AGENT);
                if (__all(v >= s + 1)) break;
                __builtin_amdgcn_s_sleep(2);
            }
            __builtin_amdgcn_fence(__ATOMIC_ACQUIRE, "agent");   // inv
        }
        __syncthreads();
    }
}

// ---------------------------------------------------------------------------
// gh_dec = enc_h @ dec_Whh^T + dec_bhh (fp32 out).
__global__ __launch_bounds__(256, 1) void gru_gemm1(
    const u16* __restrict__ WhhH, const u16* __restrict__ WhhL,
    const float* __restrict__ bhh,
    const u16* __restrict__ hin_hi, const u16* __restrict__ hin_lo,
    float* __restrict__ gh_out)
{
    __shared__ u16 WbH[48 * 264];
    __shared__ u16 WbL[48 * 264];

    const int tid  = threadIdx.x;
    const int lane = tid & 63;
    const int wave = tid >> 6;
    const int lrow = lane & 15;
    const int lk8  = lane >> 4;
    const int mt = blockIdx.x & 3;
    const int jt = blockIdx.x >> 2;
    const int m0 = mt * 64;
    const int j0 = jt * 16;

    f4v acc_r  = {0.f, 0.f, 0.f, 0.f};
    f4v acc_z  = {0.f, 0.f, 0.f, 0.f};
    f4v acc_hn = {0.f, 0.f, 0.f, 0.f};

    i4v stgH[6], stgL[6];
    #pragma unroll
    for (int i = 0; i < 6; ++i) {
        int c16 = i * 256 + tid;
        int row = c16 >> 5, p16 = c16 & 31;
        int grow = (row >> 4) * 1024 + j0 + (row & 15);
        size_t off = (size_t)grow * 1024 + p16 * 8;
        stgH[i] = *(const i4v*)(WhhH + off);
        stgL[i] = *(const i4v*)(WhhL + off);
    }
    #pragma unroll
    for (int i = 0; i < 6; ++i) {
        int c16 = i * 256 + tid;
        int row = c16 >> 5, p16 = c16 & 31;
        *(i4v*)&WbH[row * 264 + p16 * 8] = stgH[i];
        *(i4v*)&WbL[row * 264 + p16 * 8] = stgL[i];
    }
    __syncthreads();

    const size_t arow = (size_t)(m0 + wave * 16 + lrow) * 1024 + lk8 * 8;
    const u16* hp = hin_hi + arow;
    const u16* lp = hin_lo + arow;

    for (int c = 0; c < 4; ++c) {
        if (c < 3) {
            #pragma unroll
            for (int i = 0; i < 6; ++i) {
                int c16 = i * 256 + tid;
                int row = c16 >> 5, p16 = c16 & 31;
                int grow = (row >> 4) * 1024 + j0 + (row & 15);
                size_t off = (size_t)grow * 1024 + (c + 1) * 256 + p16 * 8;
                stgH[i] = *(const i4v*)(WhhH + off);
                stgL[i] = *(const i4v*)(WhhL + off);
            }
        }
        #pragma unroll
        for (int ks = 0; ks < 8; ++ks) {
            int kk = c * 256 + ks * 32;
            int bo = ks * 32 + lk8 * 8;
            s8v ahi = *(const s8v*)(hp + kk);
            s8v alo = *(const s8v*)(lp + kk);
            s8v brh = *(const s8v*)&WbH[(lrow) * 264 + bo];
            s8v brl = *(const s8v*)&WbL[(lrow) * 264 + bo];
            s8v bzh = *(const s8v*)&WbH[(16 + lrow) * 264 + bo];
            s8v bzl = *(const s8v*)&WbL[(16 + lrow) * 264 + bo];
            s8v bnh = *(const s8v*)&WbH[(32 + lrow) * 264 + bo];
            s8v bnl = *(const s8v*)&WbL[(32 + lrow) * 264 + bo];
            acc_r  = mfma16(ahi, brh, acc_r);
            acc_r  = mfma16(ahi, brl, acc_r);
            acc_r  = mfma16(alo, brh, acc_r);
            acc_z  = mfma16(ahi, bzh, acc_z);
            acc_z  = mfma16(ahi, bzl, acc_z);
            acc_z  = mfma16(alo, bzh, acc_z);
            acc_hn = mfma16(ahi, bnh, acc_hn);
            acc_hn = mfma16(ahi, bnl, acc_hn);
            acc_hn = mfma16(alo, bnh, acc_hn);
        }
        __syncthreads();
        if (c < 3) {
            #pragma unroll
            for (int i = 0; i < 6; ++i) {
                int c16 = i * 256 + tid;
                int row = c16 >> 5, p16 = c16 & 31;
                *(i4v*)&WbH[row * 264 + p16 * 8] = stgH[i];
                *(i4v*)&WbL[row * 264 + p16 * 8] = stgL[i];
            }
            __syncthreads();
        }
    }

    const int jcol = j0 + lrow;
    const float bhr = bhh[jcol];
    const float bhz = bhh[1024 + jcol];
    const float bhn = bhh[2048 + jcol];
    #pragma unroll
    for (int reg = 0; reg < 4; ++reg) {
        int brow = m0 + wave * 16 + lk8 * 4 + reg;
        gh_out[(size_t)brow * 3072 + jcol]        = acc_r[reg] + bhr;
        gh_out[(size_t)brow * 3072 + 1024 + jcol] = acc_z[reg] + bhz;
        gh_out[(size_t)brow * 3072 + 2048 + jcol] = acc_hn[reg] + bhn;
    }
}

// ---------------------------------------------------------------------------
// Fused decoder (unchanged from passing round)
__global__ __launch_bounds__(256, 1) void dec_fused(
    const u16* __restrict__ WihH, const u16* __restrict__ WihL,
    const float* __restrict__ bih,
    const float* __restrict__ xdec,
    const u16* __restrict__ ehi, const u16* __restrict__ elo,
    const float* __restrict__ gh,
    const u16* __restrict__ pWH, const u16* __restrict__ pWL,
    const float* __restrict__ pb,
    float* __restrict__ out)
{
    __shared__ u16 XdH[64 * 72];
    __shared__ u16 XdL[64 * 72];
    __shared__ u16 WiH_[192 * 72];
    __shared__ u16 WiL_[192 * 72];
    __shared__ u16 nsH[64 * 72];
    __shared__ u16 nsL[64 * 72];

    const int tid  = threadIdx.x;
    const int lane = tid & 63;
    const int wave = tid >> 6;
    const int lrow = lane & 15;
    const int lk8  = lane >> 4;
    const int b    = blockIdx.x;

    {
        int row = tid >> 2, q = tid & 3;
        const float* xr = xdec + (size_t)(b * 64 + row) * 63;
        #pragma unroll
        for (int ii = 0; ii < 16; ++ii) {
            int col = q * 16 + ii;
            float v = (col < 63) ? xr[col] : 0.f;
            u16 hh = f2b(v);
            XdH[row * 72 + col] = hh;
            XdL[row * 72 + col] = f2b(v - b2f(hh));
        }
    }

    f4v oacc[4];
    #pragma unroll
    for (int f = 0; f < 4; ++f) oacc[f] = f4v{0.f, 0.f, 0.f, 0.f};

    for (int j0 = 0; j0 < 1024; j0 += 64) {
        #pragma unroll
        for (int k = 0; k < 3; ++k) {
            int c = tid + k * 256;
            int r = c >> 2, qq = c & 3;
            int grow = (r >> 6) * 1024 + j0 + (r & 63);
            const u16* srcH = WihH + (size_t)grow * 64 + qq * 16;
            const u16* srcL = WihL + (size_t)grow * 64 + qq * 16;
            *(i4v*)&WiH_[r * 72 + qq * 16]     = *(const i4v*)srcH;
            *(i4v*)&WiH_[r * 72 + qq * 16 + 8] = *(const i4v*)(srcH + 8);
            *(i4v*)&WiL_[r * 72 + qq * 16]     = *(const i4v*)srcL;
            *(i4v*)&WiL_[r * 72 + qq * 16 + 8] = *(const i4v*)(srcL + 8);
        }
        __syncthreads();

        f4v ar[4], az[4], an[4];
        #pragma unroll
        for (int jf = 0; jf < 4; ++jf) {
            ar[jf] = f4v{0.f, 0.f, 0.f, 0.f};
            az[jf] = f4v{0.f, 0.f, 0.f, 0.f};
            an[jf] = f4v{0.f, 0.f, 0.f, 0.f};
        }
        #pragma unroll
        for (int ks = 0; ks < 2; ++ks) {
            int ao = ks * 32 + lk8 * 8;
            s8v ah = *(const s8v*)&XdH[(wave * 16 + lrow) * 72 + ao];
            s8v al = *(const s8v*)&XdL[(wave * 16 + lrow) * 72 + ao];
            #pragma unroll
            for (int jf = 0; jf < 4; ++jf) {
                s8v brh = *(const s8v*)&WiH_[(jf * 16 + lrow) * 72 + ao];
                s8v brl = *(const s8v*)&WiL_[(jf * 16 + lrow) * 72 + ao];
                s8v bzh = *(const s8v*)&WiH_[(64 + jf * 16 + lrow) * 72 + ao];
                s8v bzl = *(const s8v*)&WiL_[(64 + jf * 16 + lrow) * 72 + ao];
                s8v bnh = *(const s8v*)&WiH_[(128 + jf * 16 + lrow) * 72 + ao];
                s8v bnl = *(const s8v*)&WiL_[(128 + jf * 16 + lrow) * 72 + ao];
                ar[jf] = mfma16(ah, brh, ar[jf]);
                ar[jf] = mfma16(ah, brl, ar[jf]);
                ar[jf] = mfma16(al, brh, ar[jf]);
                az[jf] = mfma16(ah, bzh, az[jf]);
                az[jf] = mfma16(ah, bzl, az[jf]);
                az[jf] = mfma16(al, bzh, az[jf]);
                an[jf] = mfma16(ah, bnh, an[jf]);
                an[jf] = mfma16(ah, bnl, an[jf]);
                an[jf] = mfma16(al, bnh, an[jf]);
            }
        }

        #pragma unroll
        for (int jf = 0; jf < 4; ++jf) {
            int j = j0 + jf * 16 + lrow;
            float ghr = gh[(size_t)b * 3072 + j];
            float ghz = gh[(size_t)b * 3072 + 1024 + j];
            float ghn = gh[(size_t)b * 3072 + 2048 + j];
            float bir = bih[j];
            float biz = bih[1024 + j];
            float bin = bih[2048 + j];
            size_t eo = (size_t)b * 1024 + j;
            float he = b2f(ehi[eo]) + b2f(elo[eo]);
            #pragma unroll
            for (int reg = 0; reg < 4; ++reg) {
                float r  = sigf(ar[jf][reg] + bir + ghr);
                float z  = sigf(az[jf][reg] + biz + ghz);
                float nn = tanhf(an[jf][reg] + bin + r * ghn);
                float v  = (1.f - z) * nn + z * he;
                u16 hh = f2b(v);
                int lo_i = (wave * 16 + lk8 * 4 + reg) * 72 + jf * 16 + lrow;
                nsH[lo_i] = hh;
                nsL[lo_i] = f2b(v - b2f(hh));
            }
        }
        __syncthreads();

        #pragma unroll
        for (int ks = 0; ks < 2; ++ks) {
            int ao = ks * 32 + lk8 * 8;
            s8v ah = *(const s8v*)&nsH[(wave * 16 + lrow) * 72 + ao];
            s8v al = *(const s8v*)&nsL[(wave * 16 + lrow) * 72 + ao];
            #pragma unroll
            for (int f = 0; f < 4; ++f) {
                size_t bo = (size_t)(f * 16 + lrow) * 1024 + j0 + ks * 32 + lk8 * 8;
                s8v bh = *(const s8v*)(pWH + bo);
                s8v bl = *(const s8v*)(pWL + bo);
                oacc[f] = mfma16(ah, bh, oacc[f]);
                oacc[f] = mfma16(ah, bl, oacc[f]);
                oacc[f] = mfma16(al, bh, oacc[f]);
            }
        }
        __syncthreads();
    }

    #pragma unroll
    for (int f = 0; f < 4; ++f) {
        int o = f * 16 + lrow;
        if (o < 63) {
            float pbv = pb[o];
            #pragma unroll
            for (int reg = 0; reg < 4; ++reg) {
                int t = wave * 16 + lk8 * 4 + reg;
                out[((size_t)(b * 64 + t)) * 63 + o] = oacc[f][reg] + pbv;
            }
        }
    }
}

// ---------------------------------------------------------------------------
extern "C" void kernel_launch(void* const* d_in, const int* in_sizes, int n_in,
                              void* d_out, int out_size, void* d_ws, size_t ws_size,
                              hipStream_t stream)
{
    const float* enc_x = (const float*)d_in[0];
    const float* dec_x = (const float*)d_in[1];
    const float* eWih  = (const float*)d_in[2];
    const float* eWhh  = (const float*)d_in[3];
    const float* ebih  = (const float*)d_in[4];
    const float* ebhh  = (const float*)d_in[5];
    const float* dWih  = (const float*)d_in[6];
    const float* dWhh  = (const float*)d_in[7];
    const float* dbih  = (const float*)d_in[8];
    const float* dbhh  = (const float*)d_in[9];
    const float* pW    = (const float*)d_in[10];
    const float* pb    = (const float*)d_in[11];

    char* ws = (char*)d_ws;
    u16*   H0hi  = (u16*)(ws);                    // 512 KB (256 x 1024 bf16)
    u16*   H0lo  = (u16*)(ws + 524288);
    u16*   H1hi  = (u16*)(ws + 1048576);
    u16*   H1lo  = (u16*)(ws + 1572864);
    int*   ep    = (int*)(ws + 2097152);          // 256 epoch slots x 64 B
    float* ghd   = (float*)(ws + 3145728);        // 3 MB (256 x 3072 fp32)
    u16*   eWhhH = (u16*)(ws + 6291456);          // 6 MB each
    u16*   eWhhL = (u16*)(ws + 12582912);
    u16*   dWhhH = (u16*)(ws + 18874368);
    u16*   dWhhL = (u16*)(ws + 25165824);
    u16*   eWihH = (u16*)(ws + 31457280);         // 384 KB each (3072 x 64)
    u16*   eWihL = (u16*)(ws + 31850496);
    u16*   dWihH = (u16*)(ws + 32243712);
    u16*   dWihL = (u16*)(ws + 32636928);
    u16*   pWH   = (u16*)(ws + 33030144);         // 128 KB each (64 x 1024)
    u16*   pWL   = (u16*)(ws + 33161216);

    // one-time fp32 -> bf16 hi+lo weight conversions
    conv_split<<<dim3(4096), dim3(256), 0, stream>>>(eWhh, eWhhH, eWhhL, 3145728);
    conv_split<<<dim3(4096), dim3(256), 0, stream>>>(dWhh, dWhhH, dWhhL, 3145728);
    conv_wih_split_pad<<<dim3(768), dim3(256), 0, stream>>>(eWih, eWihH, eWihL);
    conv_wih_split_pad<<<dim3(768), dim3(256), 0, stream>>>(dWih, dWihH, dWihL);
    conv_pw_split_pad<<<dim3(256), dim3(256), 0, stream>>>(pW, pWH, pWL);

    // zero h buffers (2 MB) + epoch slots (16 KB)
    zero_ws<<<dim3(517), dim3(256), 0, stream>>>((i4v*)ws, 132096);

    // persistent encoder: all 128 steps, one launch
    enc_persist<<<dim3(256), dim3(512), 0, stream>>>(
        eWhhH, eWhhL, eWihH, eWihL, ebih, ebhh, enc_x,
        H0hi, H0lo, H1hi, H1lo, ep);
    // final enc_h lives in H0 (step 127 writes H0)

    // gh_dec = enc_h @ dec_Whh^T + dec_bhh
    gru_gemm1<<<dim3(256), dim3(256), 0, stream>>>(
        dWhhH, dWhhL, dbhh, H0hi, H0lo, ghd);

    // fused decoder gates + projection -> fp32 out
    dec_fused<<<dim3(256), dim3(256), 0, stream>>>(
        dWihH, dWihL, dbih, dec_x, H0hi, H0lo, ghd, pWH, pWL, pb, (float*)d_out);
}